// Round 8
// baseline (571.295 us; speedup 1.0000x reference)
//
#include <hip/hip_runtime.h>

typedef __bf16 bf16;
typedef __bf16 bf16x8 __attribute__((ext_vector_type(8)));
typedef __bf16 bf16x4 __attribute__((ext_vector_type(4)));
typedef float f32x4 __attribute__((ext_vector_type(4)));

#define S_LEN 2048
#define HID 4096
#define NH 32
#define NKV 8
#define HD 128
#define QSTR 6144                      // fused qkv row stride
#define SCALE 0.08838834764831845f
#define QSCL 0.1275164918918885f       // SCALE * log2(e)
#define M2C 16.33f                     // >= 128*QSCL = 16.3221 (Cauchy-Schwarz hard bound)

template <int V> struct IC { static constexpr int value = V; };

__device__ __forceinline__ bf16x8 load8(const bf16* p) { return *(const bf16x8*)p; }
__device__ __forceinline__ bf16x8 load8(const float* p) {
    float4 a = *(const float4*)p;
    float4 b = *(const float4*)(p + 4);
    bf16x8 r;
    r[0] = (bf16)a.x; r[1] = (bf16)a.y; r[2] = (bf16)a.z; r[3] = (bf16)a.w;
    r[4] = (bf16)b.x; r[5] = (bf16)b.y; r[6] = (bf16)b.z; r[7] = (bf16)b.w;
    return r;
}

__device__ __forceinline__ void load_lds16(const bf16* g, bf16* l) {
    __builtin_amdgcn_global_load_lds(
        (const __attribute__((address_space(1))) void*)g,
        (__attribute__((address_space(3))) void*)l, 16, 0, 0);
}

template <int C> __device__ __forceinline__ void vmwait_if() {
    if constexpr (C >= 0) asm volatile("s_waitcnt vmcnt(%0)" ::"n"(C) : "memory");
}

__device__ __forceinline__ void lgkm0() {
    asm volatile("s_waitcnt lgkmcnt(0)" ::: "memory");
    __builtin_amdgcn_sched_barrier(0);
}

// ---------------------------------------------------------------------------
// fused fp32 -> bf16 bulk convert: x | Wq | Wk | Wv -> xb,Wqkv ; Wo -> Wob
// ---------------------------------------------------------------------------
__global__ __launch_bounds__(256) void cvt5(const float* __restrict__ x,
                                            const float* __restrict__ Wq,
                                            const float* __restrict__ Wk,
                                            const float* __restrict__ Wv,
                                            const float* __restrict__ Wo,
                                            bf16* __restrict__ xb,
                                            bf16* __restrict__ Wqkv,
                                            bf16* __restrict__ Wob) {
    int i = blockIdx.x * 256 + threadIdx.x;
    const float* src;
    bf16* dst;
    if (i < 1048576)      { src = x  + (size_t)i * 8;              dst = xb + (size_t)i * 8; }
    else if (i < 3145728) { size_t j = i - 1048576; src = Wq + j * 8; dst = Wqkv + j * 8; }
    else if (i < 3670016) { size_t j = i - 3145728; src = Wk + j * 8; dst = Wqkv + 16777216 + j * 8; }
    else if (i < 4194304) { size_t j = i - 3670016; src = Wv + j * 8; dst = Wqkv + 20971520 + j * 8; }
    else                  { size_t j = i - 4194304; src = Wo + j * 8; dst = Wob + j * 8; }
    *(bf16x8*)dst = load8(src);
}

// ---------------------------------------------------------------------------
// gemmQ: m201 8-phase quadrant GEMM (proven round 6). BM=BN=256, BK=64.
// ---------------------------------------------------------------------------
template <int BMODE, typename TO>
__global__ __launch_bounds__(512, 2) void gemmQ(const bf16* __restrict__ A,
                                                const bf16* __restrict__ Bw,
                                                const float* __restrict__ b0,
                                                const float* __restrict__ b1,
                                                const float* __restrict__ b2,
                                                TO* __restrict__ out,
                                                int N, int K) {
    __shared__ __align__(16) bf16 AS[4 * 128 * 64];   // [buf*2+half][r][64]
    __shared__ __align__(16) bf16 BS[4 * 128 * 64];

    const int tid  = threadIdx.x;
    const int wave = tid >> 6;
    const int lane = tid & 63;
    const int quad = lane >> 4;
    const int l16  = lane & 15;
    const int wm   = wave >> 2;
    const int wn   = wave & 3;

    const int gx   = gridDim.x;
    const int nwg  = gx * gridDim.y;
    const int orig = blockIdx.y * gx + blockIdx.x;
    int wg = orig;
    if ((nwg & 7) == 0) wg = (orig & 7) * (nwg >> 3) + (orig >> 3);
    const int row0 = (wg / gx) * 256;
    const int col0 = (wg % gx) * 256;

    auto stageA = [&](int h, int bufv, int kt) {
#pragma unroll
        for (int j = 0; j < 2; ++j) {
            int c = j * 512 + tid;
            int r = c >> 3, pg = c & 7;
            int g = pg ^ (r & 7);
            int gr = (r >> 6) * 128 + h * 64 + (r & 63);
            load_lds16(&A[(size_t)(row0 + gr) * K + kt * 64 + g * 8],
                       &AS[(bufv * 2 + h) * 8192 + c * 8]);
        }
    };
    auto stageB = [&](int nh, int bufv, int kt) {
#pragma unroll
        for (int j = 0; j < 2; ++j) {
            int c = j * 512 + tid;
            int r = c >> 3, pg = c & 7;
            int g = pg ^ (r & 7);
            int gc = (r >> 5) * 64 + nh * 32 + (r & 31);
            load_lds16(&Bw[(size_t)(col0 + gc) * K + kt * 64 + g * 8],
                       &BS[(bufv * 2 + nh) * 8192 + c * 8]);
        }
    };

    f32x4 acc[8][4];
#pragma unroll
    for (int a = 0; a < 8; ++a)
#pragma unroll
        for (int b = 0; b < 4; ++b) { f32x4 z = {0.f, 0.f, 0.f, 0.f}; acc[a][b] = z; }

    bf16x8 afr[4][2];
    bf16x8 bfr[2][2][2];

    auto loadAh = [&](int h, int bufv) {
#pragma unroll
        for (int mi = 0; mi < 4; ++mi)
#pragma unroll
            for (int ks = 0; ks < 2; ++ks) {
                int r = wm * 64 + mi * 16 + l16;
                int gg = ks * 4 + quad;
                afr[mi][ks] = *(const bf16x8*)&AS[(bufv * 2 + h) * 8192 + r * 64 +
                                                  ((gg ^ (r & 7)) << 3)];
            }
    };
    auto loadBh = [&](auto cNQ, int bufv) {
        constexpr int NQ = decltype(cNQ)::value;
#pragma unroll
        for (int ni = 0; ni < 2; ++ni)
#pragma unroll
            for (int ks = 0; ks < 2; ++ks) {
                int r = wn * 32 + ni * 16 + l16;
                int gg = ks * 4 + quad;
                bfr[NQ][ni][ks] = *(const bf16x8*)&BS[(bufv * 2 + NQ) * 8192 + r * 64 +
                                                      ((gg ^ (r & 7)) << 3)];
            }
    };
    auto mmac = [&](auto cMQ, auto cNQ) {
        constexpr int MQ = decltype(cMQ)::value, NQ = decltype(cNQ)::value;
        __builtin_amdgcn_s_setprio(1);
#pragma unroll
        for (int mi = 0; mi < 4; ++mi)
#pragma unroll
            for (int ni = 0; ni < 2; ++ni)
#pragma unroll
                for (int ks = 0; ks < 2; ++ks)
                    acc[MQ * 4 + mi][NQ * 2 + ni] = __builtin_amdgcn_mfma_f32_16x16x32_bf16(
                        afr[mi][ks], bfr[NQ][ni][ks], acc[MQ * 4 + mi][NQ * 2 + ni], 0, 0, 0);
        __builtin_amdgcn_s_setprio(0);
    };

    auto run_iter = [&](int t0, auto cST, auto cV3, auto cV7) {
        constexpr bool ST = decltype(cST)::value != 0;
        // p0 (buf0, m0n0)
        stageA(1, 1, t0 + 1);
        loadAh(0, 0);
        loadBh(IC<0>{}, 0);
        __builtin_amdgcn_s_barrier();
        lgkm0();
        mmac(IC<0>{}, IC<0>{});
        __builtin_amdgcn_s_barrier();
        // p1 (m0n1)
        if constexpr (ST) stageA(0, 0, t0 + 2);
        loadBh(IC<1>{}, 0);
        __builtin_amdgcn_s_barrier();
        lgkm0();
        mmac(IC<0>{}, IC<1>{});
        __builtin_amdgcn_s_barrier();
        // p2 (m1n0)
        if constexpr (ST) stageB(0, 0, t0 + 2);
        loadAh(1, 0);
        __builtin_amdgcn_s_barrier();
        lgkm0();
        mmac(IC<1>{}, IC<0>{});
        __builtin_amdgcn_s_barrier();
        // p3 (m1n1)
        if constexpr (ST) stageB(1, 0, t0 + 2);
        __builtin_amdgcn_s_barrier();
        mmac(IC<1>{}, IC<1>{});
        vmwait_if<decltype(cV3)::value>();
        __builtin_amdgcn_s_barrier();
        // p4 (buf1, m0n0)
        if constexpr (ST) stageA(1, 0, t0 + 2);
        loadAh(0, 1);
        loadBh(IC<0>{}, 1);
        __builtin_amdgcn_s_barrier();
        lgkm0();
        mmac(IC<0>{}, IC<0>{});
        __builtin_amdgcn_s_barrier();
        // p5 (m0n1)
        if constexpr (ST) stageA(0, 1, t0 + 3);
        loadBh(IC<1>{}, 1);
        __builtin_amdgcn_s_barrier();
        lgkm0();
        mmac(IC<0>{}, IC<1>{});
        __builtin_amdgcn_s_barrier();
        // p6 (m1n0)
        if constexpr (ST) stageB(0, 1, t0 + 3);
        loadAh(1, 1);
        __builtin_amdgcn_s_barrier();
        lgkm0();
        mmac(IC<1>{}, IC<0>{});
        __builtin_amdgcn_s_barrier();
        // p7 (m1n1)
        if constexpr (ST) stageB(1, 1, t0 + 3);
        __builtin_amdgcn_s_barrier();
        mmac(IC<1>{}, IC<1>{});
        vmwait_if<decltype(cV7)::value>();
        __builtin_amdgcn_s_barrier();
    };

    stageA(0, 0, 0); stageB(0, 0, 0); stageB(1, 0, 0); stageA(1, 0, 0);
    stageA(0, 1, 1); stageB(0, 1, 1); stageB(1, 1, 1);
    vmwait_if<6>();
    __builtin_amdgcn_s_barrier();

    const int NT = K >> 6;
    for (int t0 = 0; t0 < NT - 2; t0 += 2)
        run_iter(t0, IC<1>{}, IC<6>{}, IC<6>{});
    run_iter(NT - 2, IC<0>{}, IC<0>{}, IC<-1>{});

#pragma unroll
    for (int mq = 0; mq < 2; ++mq)
#pragma unroll
        for (int nq = 0; nq < 2; ++nq)
#pragma unroll
            for (int ni = 0; ni < 2; ++ni) {
                int n = col0 + wn * 64 + nq * 32 + ni * 16 + l16;
                float bv;
                if (BMODE == 0) bv = b0[n];
                else bv = (n < 4096) ? b0[n] : ((n < 5120) ? b1[n - 4096] : b2[n - 5120]);
#pragma unroll
                for (int mi = 0; mi < 4; ++mi) {
                    int m = row0 + wm * 128 + mq * 64 + mi * 16 + quad * 4;
#pragma unroll
                    for (int reg = 0; reg < 4; ++reg)
                        out[(size_t)(m + reg) * N + n] =
                            (TO)(acc[mq * 4 + mi][nq * 2 + ni][reg] + bv);
                }
            }
}

// ---------------------------------------------------------------------------
// gemm8 (proven round-2/3): 8-phase pipelined GEMM for the output projection.
// ---------------------------------------------------------------------------
template <int BM, int BN, int WM, int WN, int BMODE, typename TO>
__global__ __launch_bounds__(512, 2) void gemm8(const bf16* __restrict__ A,
                                                const bf16* __restrict__ Bw,
                                                const float* __restrict__ b0,
                                                const float* __restrict__ b1,
                                                const float* __restrict__ b2,
                                                TO* __restrict__ out,
                                                int N, int K) {
    constexpr int RW  = BM / WM;
    constexpr int CW  = BN / WN;
    constexpr int FM  = RW / 16;
    constexpr int FN  = CW / 16;
    constexpr int FMH = FM / 2;
    constexpr int FNH0 = (FN + 1) / 2, FNH1 = FN - FNH0;
    constexpr int SZ0 = FNH0 * 16, SZ1 = FNH1 * 16;
    constexpr int AROWS_H = BM / 2;
    constexpr int B0ROWS = WN * SZ0, B1ROWS = WN * SZ1;
    constexpr int LA  = AROWS_H / 64;
    constexpr int LB0 = B0ROWS / 64, LB1 = B1ROWS / 64;
    constexpr int V0  = 2 * LA + LB0;
    constexpr int V3  = 2 * LA + LB0 + LB1;
    constexpr int V3T = LA + LB1;

    __shared__ __align__(16) bf16 AS[2 * BM * 64];
    __shared__ __align__(16) bf16 BS[2 * BN * 64];

    const int tid  = threadIdx.x;
    const int wave = tid >> 6;
    const int lane = tid & 63;
    const int quad = lane >> 4;
    const int l16  = lane & 15;
    const int wm   = wave / WN;
    const int wn   = wave % WN;

    const int gx   = gridDim.x;
    const int nwg  = gx * gridDim.y;
    const int orig = blockIdx.y * gx + blockIdx.x;
    int wg = orig;
    if ((nwg & 7) == 0) wg = (orig & 7) * (nwg >> 3) + (orig >> 3);
    const int row0 = (wg / gx) * BM;
    const int col0 = (wg % gx) * BN;

    auto stageA = [&](int mh, int bufv, int kt) {
#pragma unroll
        for (int j = 0; j < LA; ++j) {
            int c = j * 512 + tid;
            int r = c >> 3, pg = c & 7;
            int g = pg ^ (r & 7);
            int gr = (r / (RW / 2)) * RW + mh * (RW / 2) + (r % (RW / 2));
            load_lds16(&A[(size_t)(row0 + gr) * K + kt * 64 + g * 8],
                       &AS[bufv * (BM * 64) + mh * (AROWS_H * 64) + c * 8]);
        }
    };
    auto stageB0 = [&](int bufv, int kt) {
#pragma unroll
        for (int j = 0; j < LB0; ++j) {
            int c = j * 512 + tid;
            int r = c >> 3, pg = c & 7;
            int g = pg ^ (r & 7);
            int gc = (r / SZ0) * CW + (r % SZ0);
            load_lds16(&Bw[(size_t)(col0 + gc) * K + kt * 64 + g * 8],
                       &BS[bufv * (BN * 64) + c * 8]);
        }
    };
    auto stageB1 = [&](int bufv, int kt) {
#pragma unroll
        for (int j = 0; j < LB1; ++j) {
            int c = j * 512 + tid;
            int r = c >> 3, pg = c & 7;
            int g = pg ^ (r & 7);
            int gc = (r / SZ1) * CW + SZ0 + (r % SZ1);
            load_lds16(&Bw[(size_t)(col0 + gc) * K + kt * 64 + g * 8],
                       &BS[bufv * (BN * 64) + B0ROWS * 64 + c * 8]);
        }
    };

    f32x4 acc[FM][FN];
#pragma unroll
    for (int mi = 0; mi < FM; ++mi)
#pragma unroll
        for (int ni = 0; ni < FN; ++ni) { f32x4 z = {0.f, 0.f, 0.f, 0.f}; acc[mi][ni] = z; }

    bf16x8 af[FMH][2];
    bf16x8 bfv[FN][2];

    auto loadA = [&](int mh, int bufv) {
#pragma unroll
        for (int mi = 0; mi < FMH; ++mi)
#pragma unroll
            for (int ks = 0; ks < 2; ++ks) {
                int r = wm * (RW / 2) + mi * 16 + l16;
                int g = ks * 4 + quad;
                af[mi][ks] = *(const bf16x8*)&AS[bufv * (BM * 64) + mh * (AROWS_H * 64) +
                                                 r * 64 + ((g ^ (r & 7)) << 3)];
            }
    };
    auto loadB = [&](auto cNH, int bufv) {
        constexpr int NHv = decltype(cNH)::value;
        constexpr int CNT = NHv ? FNH1 : FNH0;
        constexpr int SZ  = NHv ? SZ1 : SZ0;
#pragma unroll
        for (int nj = 0; nj < CNT; ++nj)
#pragma unroll
            for (int ks = 0; ks < 2; ++ks) {
                int r = wn * SZ + nj * 16 + l16;
                int g = ks * 4 + quad;
                bfv[NHv * FNH0 + nj][ks] =
                    *(const bf16x8*)&BS[bufv * (BN * 64) + NHv * (B0ROWS * 64) +
                                        r * 64 + ((g ^ (r & 7)) << 3)];
            }
    };
    auto mmac = [&](auto cMH, auto cNH) {
        constexpr int MH = decltype(cMH)::value, NHv = decltype(cNH)::value;
        constexpr int NB = NHv ? FNH0 : 0, NE = NHv ? FN : FNH0;
        __builtin_amdgcn_s_setprio(1);
#pragma unroll
        for (int mi = 0; mi < FMH; ++mi)
#pragma unroll
            for (int ni = NB; ni < NE; ++ni)
#pragma unroll
                for (int ks = 0; ks < 2; ++ks)
                    acc[MH * FMH + mi][ni] = __builtin_amdgcn_mfma_f32_16x16x32_bf16(
                        af[mi][ks], bfv[ni][ks], acc[MH * FMH + mi][ni], 0, 0, 0);
        __builtin_amdgcn_s_setprio(0);
    };

    auto run_tile = [&](int t, auto cSA1, auto cSB1, auto cSA0, auto cSB0,
                        auto cV0, auto cV3) {
        const int buf = t & 1, nbuf = buf ^ 1;
        loadA(0, buf);
        loadB(IC<0>{}, buf);
        if constexpr (decltype(cSA1)::value) stageA(1, nbuf, t + 1);
        __builtin_amdgcn_s_barrier();
        lgkm0();
        mmac(IC<0>{}, IC<0>{});
        vmwait_if<decltype(cV0)::value>();
        __builtin_amdgcn_s_barrier();
        loadB(IC<1>{}, buf);
        if constexpr (decltype(cSB1)::value) stageB1(nbuf, t + 1);
        __builtin_amdgcn_s_barrier();
        lgkm0();
        mmac(IC<0>{}, IC<1>{});
        __builtin_amdgcn_s_barrier();
        loadA(1, buf);
        if constexpr (decltype(cSA0)::value) stageA(0, buf, t + 2);
        __builtin_amdgcn_s_barrier();
        lgkm0();
        mmac(IC<1>{}, IC<0>{});
        __builtin_amdgcn_s_barrier();
        if constexpr (decltype(cSB0)::value) stageB0(buf, t + 2);
        __builtin_amdgcn_s_barrier();
        lgkm0();
        mmac(IC<1>{}, IC<1>{});
        vmwait_if<decltype(cV3)::value>();
        __builtin_amdgcn_s_barrier();
    };

    stageA(0, 0, 0); stageB0(0, 0);
    stageA(1, 0, 0); stageB1(0, 0);
    stageA(0, 1, 1); stageB0(1, 1);
    vmwait_if<V3>();
    __builtin_amdgcn_s_barrier();

    const int NT = K >> 6;
    for (int t = 0; t < NT - 2; ++t)
        run_tile(t, IC<1>{}, IC<1>{}, IC<1>{}, IC<1>{}, IC<V0>{}, IC<V3>{});
    run_tile(NT - 2, IC<1>{}, IC<1>{}, IC<0>{}, IC<0>{}, IC<V0>{}, IC<V3T>{});
    run_tile(NT - 1, IC<0>{}, IC<0>{}, IC<0>{}, IC<0>{}, IC<0>{}, IC<-1>{});

#pragma unroll
    for (int ni = 0; ni < FN; ++ni) {
        int n = col0 + wn * CW + ni * 16 + l16;
        float bv;
        if (BMODE == 0) bv = b0[n];
        else bv = (n < 4096) ? b0[n] : ((n < 5120) ? b1[n - 4096] : b2[n - 5120]);
#pragma unroll
        for (int mi = 0; mi < FM; ++mi) {
            int m = row0 + wm * RW + mi * 16 + quad * 4;
#pragma unroll
            for (int reg = 0; reg < 4; ++reg)
                out[(size_t)(m + reg) * N + n] = (TO)(acc[mi][ni][reg] + bv);
        }
    }
}

// ---------------------------------------------------------------------------
// LayerNorm(HD=128) + RoPE in place on fused qkv buffer (stride QSTR).
// ---------------------------------------------------------------------------
__global__ __launch_bounds__(256) void ln_rope(bf16* __restrict__ qkv,
                                               const float* __restrict__ qg, const float* __restrict__ qbt,
                                               const float* __restrict__ kg, const float* __restrict__ kbt) {
    int row  = blockIdx.x * 4 + (threadIdx.x >> 6);
    int lane = threadIdx.x & 63;

    bf16* ptr;
    const float *g, *bb;
    int s;
    float osc;
    if (row < S_LEN * NH) {
        s   = row >> 5;
        ptr = qkv + (size_t)s * QSTR + (row & 31) * HD;
        g   = qg; bb = qbt; osc = QSCL;
    } else {
        int r2 = row - S_LEN * NH;
        s   = r2 >> 3;
        ptr = qkv + (size_t)s * QSTR + 4096 + (r2 & 7) * HD;
        g   = kg; bb = kbt; osc = 1.f;
    }

    float x1 = (float)ptr[lane];
    float x2 = (float)ptr[lane + 64];
    float sum = x1 + x2;
    float sq  = x1 * x1 + x2 * x2;
#pragma unroll
    for (int m = 1; m < 64; m <<= 1) {
        sum += __shfl_xor(sum, m);
        sq  += __shfl_xor(sq, m);
    }
    float mu  = sum * (1.f / 128.f);
    float var = sq * (1.f / 128.f) - mu * mu;
    float rs  = rsqrtf(var + 1e-5f);
    float n1  = (x1 - mu) * rs * g[lane] + bb[lane];
    float n2  = (x2 - mu) * rs * g[lane + 64] + bb[lane + 64];

    float inv = exp2f(-0.2958057514f * (float)lane);
    float ang = (float)s * inv;
    float sn, cs;
    sincosf(ang, &sn, &cs);

    ptr[lane]      = (bf16)((n1 * cs - n2 * sn) * osc);
    ptr[lane + 64] = (bf16)((n2 * cs + n1 * sn) * osc);
}

// ---------------------------------------------------------------------------
// Transpose v (cols 5120..6143 of qkv, [s][c]) -> vT [c][s].
// ---------------------------------------------------------------------------
__global__ __launch_bounds__(256) void transpose_v(const bf16* __restrict__ qkv,
                                                   bf16* __restrict__ vT) {
    __shared__ bf16 Ts[64 * 64];
    const int c0 = blockIdx.x * 64;
    const int s0 = blockIdx.y * 64;
    const int tid = threadIdx.x;

#pragma unroll
    for (int i = 0; i < 2; ++i) {
        int cc = i * 256 + tid;
        int r = cc >> 3, col8 = cc & 7;
        *(bf16x8*)&Ts[r * 64 + ((col8 ^ (r & 7)) << 3)] =
            *(const bf16x8*)&qkv[(size_t)(s0 + r) * QSTR + 5120 + c0 + (col8 << 3)];
    }
    __syncthreads();
#pragma unroll
    for (int i = 0; i < 2; ++i) {
        int oc = i * 256 + tid;
        int c = oc & 63, sb = oc >> 6;
        bf16x8 r8;
#pragma unroll
        for (int j = 0; j < 8; ++j) {
            int sg = sb * 8 + j;
            r8[j] = Ts[sg * 64 + ((((c >> 3) ^ (sg & 7)) << 3) + (c & 7))];
        }
        *(bf16x8*)&vT[(size_t)(c0 + c) * S_LEN + s0 + sb * 8] = r8;
    }
}

// ---------------------------------------------------------------------------
// Flash attention v5: full-Q blocks, 2 independent blocks/CU, no merge.
// Block = (qt, kvh), 256 threads = 4 waves = 4 heads. Walks kt=0..nkt-1 with
// double-buffered K/V LDS (ONE barrier/iter: drain(t+1) -> other buf during
// compute(t); WAR/RAW separated by the single end-of-iter barrier). LDS =
// 80 KiB exactly -> 2 blocks/CU: each SIMD hosts waves of two independent
// barrier groups (anti-correlated stalls). Complement block mapping pairs
// (qt, 63-qt) on the likely (c, c+256) CU assignment -> ~33 iters/CU.
// Fixed-max log2 softmax + MFMA ones-trick row sums (proven attn3 math).
// ---------------------------------------------------------------------------
__global__ __launch_bounds__(256, 2) void attn5(const bf16* __restrict__ qkv,
                                                const bf16* __restrict__ vT,
                                                bf16* __restrict__ abuf) {
    const int lin = blockIdx.y * 64 + blockIdx.x;
    int qt, kvh;
    if (lin < 256) { qt = lin & 63;        kvh = lin >> 6; }
    else           { qt = 63 - (lin & 63); kvh = 4 + ((lin - 256) >> 6); }

    const int tid  = threadIdx.x;
    const int wave = tid >> 6;         // head within kv group
    const int lane = tid & 63;
    const int quad = lane >> 4;
    const int l16  = lane & 15;
    const int h    = kvh * 4 + wave;
    const int r0   = qt * 32;
    const int nkt  = qt / 2 + 1;

    // LDS: K[2][64*128] | V[2][128*64] | Ps[4][32*64]  = 80 KiB exactly
    __shared__ __align__(16) bf16 smem[2 * 8192 + 2 * 8192 + 4 * 2048];
    bf16* Ksb = smem;                  // per-buf stride 8192
    bf16* Vtb = smem + 2 * 8192;
    bf16* Psb = smem + 4 * 8192;       // per-wave stride 2048

    bf16x8 onesf;
#pragma unroll
    for (int j = 0; j < 8; ++j) onesf[j] = (bf16)1.f;

    // Q fragments (already scaled by QSCL in ln_rope)
    bf16x8 qf[2][4];
#pragma unroll
    for (int mi = 0; mi < 2; ++mi)
#pragma unroll
        for (int ks = 0; ks < 4; ++ks)
            qf[mi][ks] = *(const bf16x8*)&qkv[(size_t)(r0 + mi * 16 + l16) * QSTR +
                                              h * HD + ks * 32 + quad * 8];

    f32x4 o_acc[2][8];
#pragma unroll
    for (int mi = 0; mi < 2; ++mi)
#pragma unroll
        for (int ni = 0; ni < 8; ++ni) {
            f32x4 z = {0.f, 0.f, 0.f, 0.f};
            o_acc[mi][ni] = z;
        }
    f32x4 lacc[2];
#pragma unroll
    for (int mi = 0; mi < 2; ++mi) { f32x4 z = {0.f, 0.f, 0.f, 0.f}; lacc[mi] = z; }

    int4 pk[4], pv[4];
    auto load_regs = [&](int kt) {
#pragma unroll
        for (int i = 0; i < 4; ++i) {
            int cc = i * 256 + tid;
            int key = cc >> 4, d8 = cc & 15;
            pk[i] = *(const int4*)&qkv[(size_t)(kt * 64 + key) * QSTR + 4096 +
                                       kvh * HD + (d8 << 3)];
        }
#pragma unroll
        for (int i = 0; i < 4; ++i) {
            int cc = i * 256 + tid;
            int d = cc >> 3, k8 = cc & 7;
            pv[i] = *(const int4*)&vT[(size_t)(kvh * HD + d) * S_LEN + kt * 64 + (k8 << 3)];
        }
    };
    auto drain = [&](int b) {
#pragma unroll
        for (int i = 0; i < 4; ++i) {
            int cc = i * 256 + tid;
            int key = cc >> 4, d8 = cc & 15;
            *(int4*)&Ksb[b * 8192 + key * 128 + ((d8 ^ (key & 7)) << 3)] = pk[i];
        }
#pragma unroll
        for (int i = 0; i < 4; ++i) {
            int cc = i * 256 + tid;
            int d = cc >> 3, k8 = cc & 7;
            *(int4*)&Vtb[b * 8192 + d * 64 + ((k8 ^ (d & 7)) << 3)] = pv[i];
        }
    };

    // prologue: tile 0 -> buf 0
    load_regs(0);
    drain(0);
    __syncthreads();

    for (int kt = 0; kt < nkt; ++kt) {
        const int b = kt & 1;
        if (kt + 1 < nkt) load_regs(kt + 1);   // issue early; lands during compute

        const bf16* Kw = Ksb + b * 8192;
        const bf16* Vw = Vtb + b * 8192;
        bf16* Pw = Psb + wave * 2048;

        // S = Q K^T (log2-scaled)
        f32x4 sacc[2][4];
#pragma unroll
        for (int mi = 0; mi < 2; ++mi)
#pragma unroll
            for (int ni = 0; ni < 4; ++ni) {
                f32x4 z = {0.f, 0.f, 0.f, 0.f};
                sacc[mi][ni] = z;
            }
        __builtin_amdgcn_s_setprio(1);
#pragma unroll
        for (int ks = 0; ks < 4; ++ks)
#pragma unroll
            for (int ni = 0; ni < 4; ++ni) {
                bf16x8 kf = *(const bf16x8*)&Kw[(ni * 16 + l16) * 128 +
                                                ((((ks << 2) + quad) ^ (l16 & 7)) << 3)];
                sacc[0][ni] = __builtin_amdgcn_mfma_f32_16x16x32_bf16(qf[0][ks], kf, sacc[0][ni], 0, 0, 0);
                sacc[1][ni] = __builtin_amdgcn_mfma_f32_16x16x32_bf16(qf[1][ks], kf, sacc[1][ni], 0, 0, 0);
            }
        __builtin_amdgcn_s_setprio(0);

        // fixed-max softmax: p = exp2(s2 - M2C); masked -> 0
#pragma unroll
        for (int mi = 0; mi < 2; ++mi)
#pragma unroll
            for (int reg = 0; reg < 4; ++reg) {
                int rloc = mi * 16 + quad * 4 + reg;
                int qrow = r0 + rloc;
#pragma unroll
                for (int ni = 0; ni < 4; ++ni) {
                    int key = kt * 64 + ni * 16 + l16;
                    float t = (key > qrow) ? -1e30f : (sacc[mi][ni][reg] - M2C);
                    float p = exp2f(t);
                    int blk = (ni * 2 + (l16 >> 3)) ^ (rloc & 7);
                    Pw[rloc * 64 + blk * 8 + (l16 & 7)] = (bf16)p;
                }
            }

        // O += P @ V ; l += P @ ones   (per-wave Ps: no barrier needed)
        __builtin_amdgcn_s_setprio(1);
#pragma unroll
        for (int ks2 = 0; ks2 < 2; ++ks2) {
            bf16x8 pa[2];
#pragma unroll
            for (int mi = 0; mi < 2; ++mi) {
                int rloc = mi * 16 + l16;
                pa[mi] = *(const bf16x8*)&Pw[rloc * 64 +
                                             ((((ks2 << 2) + quad) ^ (rloc & 7)) << 3)];
            }
#pragma unroll
            for (int ni = 0; ni < 8; ++ni) {
                int d = ni * 16 + l16;
                bf16x8 vf = *(const bf16x8*)&Vw[d * 64 + ((((ks2 << 2) + quad) ^ (d & 7)) << 3)];
                o_acc[0][ni] = __builtin_amdgcn_mfma_f32_16x16x32_bf16(pa[0], vf, o_acc[0][ni], 0, 0, 0);
                o_acc[1][ni] = __builtin_amdgcn_mfma_f32_16x16x32_bf16(pa[1], vf, o_acc[1][ni], 0, 0, 0);
            }
            lacc[0] = __builtin_amdgcn_mfma_f32_16x16x32_bf16(pa[0], onesf, lacc[0], 0, 0, 0);
            lacc[1] = __builtin_amdgcn_mfma_f32_16x16x32_bf16(pa[1], onesf, lacc[1], 0, 0, 0);
        }
        __builtin_amdgcn_s_setprio(0);

        // drain next tile into the other buffer (WAR safe: last readers of
        // that buffer passed the end-of-(kt-1) barrier)
        if (kt + 1 < nkt) drain(b ^ 1);
        __syncthreads();
    }

    // epilogue: normalize and write bf16 directly (no merge)
#pragma unroll
    for (int mi = 0; mi < 2; ++mi) {
        float linv[4];
#pragma unroll
        for (int reg = 0; reg < 4; ++reg)
            linv[reg] = 1.f / fmaxf(lacc[mi][reg], 1e-30f);
#pragma unroll
        for (int reg = 0; reg < 4; ++reg) {
            int s = r0 + mi * 16 + quad * 4 + reg;
#pragma unroll
            for (int ni = 0; ni < 8; ++ni)
                abuf[(size_t)s * HID + h * HD + ni * 16 + l16] =
                    (bf16)(o_acc[mi][ni][reg] * linv[reg]);
        }
    }
}

// ===========================================================================
// Fallback path — only if workspace is unexpectedly small.
// ===========================================================================
template <typename TA, typename TO>
__global__ __launch_bounds__(256) void gemm_bt(const TA* __restrict__ A,
                                               const float* __restrict__ W,
                                               const float* __restrict__ bias,
                                               TO* __restrict__ out,
                                               int N, int K) {
    __shared__ __align__(16) bf16 As[128 * 64];
    __shared__ __align__(16) bf16 Bs[128 * 64];
    const int tid = threadIdx.x, wave = tid >> 6, lane = tid & 63;
    const int quad = lane >> 4, l16 = lane & 15, wm = wave >> 1, wn = wave & 1;
    const int row0 = blockIdx.y * 128, col0 = blockIdx.x * 128;
    f32x4 acc[4][4];
#pragma unroll
    for (int mi = 0; mi < 4; ++mi)
#pragma unroll
        for (int ni = 0; ni < 4; ++ni) { f32x4 z = {0.f,0.f,0.f,0.f}; acc[mi][ni] = z; }
    for (int k0 = 0; k0 < K; k0 += 64) {
#pragma unroll
        for (int i = 0; i < 4; ++i) {
            int c = i * 256 + tid, r = c >> 3, col8 = (c & 7) << 3;
            *(bf16x8*)&As[r * 64 + col8] = load8(&A[(size_t)(row0 + r) * K + k0 + col8]);
            *(bf16x8*)&Bs[r * 64 + col8] = load8(&W[(size_t)(col0 + r) * K + k0 + col8]);
        }
        __syncthreads();
#pragma unroll
        for (int ks = 0; ks < 2; ++ks) {
            bf16x8 af[4], bfr[4];
#pragma unroll
            for (int mi = 0; mi < 4; ++mi)
                af[mi] = *(const bf16x8*)&As[(wm * 64 + mi * 16 + l16) * 64 + ks * 32 + quad * 8];
#pragma unroll
            for (int ni = 0; ni < 4; ++ni)
                bfr[ni] = *(const bf16x8*)&Bs[(wn * 64 + ni * 16 + l16) * 64 + ks * 32 + quad * 8];
#pragma unroll
            for (int mi = 0; mi < 4; ++mi)
#pragma unroll
                for (int ni = 0; ni < 4; ++ni)
                    acc[mi][ni] = __builtin_amdgcn_mfma_f32_16x16x32_bf16(af[mi], bfr[ni], acc[mi][ni], 0, 0, 0);
        }
        __syncthreads();
    }
#pragma unroll
    for (int ni = 0; ni < 4; ++ni) {
        int n = col0 + wn * 64 + ni * 16 + l16;
        float bv = bias[n];
#pragma unroll
        for (int mi = 0; mi < 4; ++mi) {
            int m = row0 + wm * 64 + mi * 16 + quad * 4;
#pragma unroll
            for (int reg = 0; reg < 4; ++reg)
                out[(size_t)(m + reg) * N + n] = (TO)(acc[mi][ni][reg] + bv);
        }
    }
}

__global__ __launch_bounds__(256) void ln_rope_f(bf16* __restrict__ qb, bf16* __restrict__ kb,
                                                 const float* __restrict__ qg, const float* __restrict__ qbt,
                                                 const float* __restrict__ kg, const float* __restrict__ kbt) {
    int row = blockIdx.x * 4 + (threadIdx.x >> 6);
    int lane = threadIdx.x & 63;
    bf16* ptr; const float *g, *bb; int s;
    if (row < S_LEN * NH) { s = row >> 5; ptr = qb + (size_t)s * (NH * HD) + (row & 31) * HD; g = qg; bb = qbt; }
    else { int r2 = row - S_LEN * NH; s = r2 >> 3; ptr = kb + (size_t)s * (NKV * HD) + (r2 & 7) * HD; g = kg; bb = kbt; }
    float x1 = (float)ptr[lane], x2 = (float)ptr[lane + 64];
    float sum = x1 + x2, sq = x1 * x1 + x2 * x2;
#pragma unroll
    for (int m = 1; m < 64; m <<= 1) { sum += __shfl_xor(sum, m); sq += __shfl_xor(sq, m); }
    float mu = sum * (1.f / 128.f), var = sq * (1.f / 128.f) - mu * mu;
    float rs = rsqrtf(var + 1e-5f);
    float n1 = (x1 - mu) * rs * g[lane] + bb[lane];
    float n2 = (x2 - mu) * rs * g[lane + 64] + bb[lane + 64];
    float inv = powf(500000.f, -(float)lane * (1.f / 64.f));
    float ang = (float)s * inv, sn, cs;
    sincosf(ang, &sn, &cs);
    ptr[lane] = (bf16)(n1 * cs - n2 * sn);
    ptr[lane + 64] = (bf16)(n2 * cs + n1 * sn);
}

__global__ __launch_bounds__(256) void attn_old(const bf16* __restrict__ qbuf,
                                                const bf16* __restrict__ kbuf,
                                                const bf16* __restrict__ vbuf,
                                                bf16* __restrict__ obuf) {
    const int qi = blockIdx.x, hh = blockIdx.y, kvh = hh >> 2;
    __shared__ __align__(16) bf16 Qs[64 * 128];
    __shared__ __align__(16) bf16 Ks2[64 * 128];
    __shared__ __align__(16) bf16 Vt2[128 * 80];
    __shared__ __align__(16) float Ss[64 * 64];
    __shared__ __align__(16) bf16 Ps2[64 * 64];
    __shared__ float mS[64], lS[64], aS[64];
    const int tid = threadIdx.x, wave = tid >> 6, lane = tid & 63;
    const int quad = lane >> 4, l16 = lane & 15;
#pragma unroll
    for (int i = 0; i < 4; ++i) {
        int c = i * 256 + tid, r = c >> 4, col8 = (c & 15) << 3;
        *(int4*)&Qs[r * 128 + col8] = *(const int4*)&qbuf[(size_t)(qi * 64 + r) * HID + hh * HD + col8];
    }
    if (tid < 64) { mS[tid] = -1e30f; lS[tid] = 0.f; }
    f32x4 o_acc[8];
#pragma unroll
    for (int i = 0; i < 8; ++i) { f32x4 z = {0.f,0.f,0.f,0.f}; o_acc[i] = z; }
    __syncthreads();
    for (int kt = 0; kt <= qi; ++kt) {
#pragma unroll
        for (int i = 0; i < 4; ++i) {
            int c = i * 256 + tid, r = c >> 4, col8 = (c & 15) << 3;
            const size_t gofs = (size_t)(kt * 64 + r) * (NKV * HD) + kvh * HD + col8;
            *(int4*)&Ks2[r * 128 + col8] = *(const int4*)&kbuf[gofs];
            bf16x8 vv = *(const bf16x8*)&vbuf[gofs];
#pragma unroll
            for (int e = 0; e < 8; ++e) Vt2[(col8 + e) * 80 + r] = vv[e];
        }
        __syncthreads();
        f32x4 sacc[4];
#pragma unroll
        for (int ni = 0; ni < 4; ++ni) { f32x4 z = {0.f,0.f,0.f,0.f}; sacc[ni] = z; }
#pragma unroll
        for (int ks = 0; ks < 4; ++ks) {
            bf16x8 a = *(const bf16x8*)&Qs[(wave * 16 + l16) * 128 + ks * 32 + quad * 8];
#pragma unroll
            for (int ni = 0; ni < 4; ++ni) {
                bf16x8 b = *(const bf16x8*)&Ks2[(ni * 16 + l16) * 128 + ks * 32 + quad * 8];
                sacc[ni] = __builtin_amdgcn_mfma_f32_16x16x32_bf16(a, b, sacc[ni], 0, 0, 0);
            }
        }
#pragma unroll
        for (int ni = 0; ni < 4; ++ni)
#pragma unroll
            for (int reg = 0; reg < 4; ++reg) {
                int r = wave * 16 + quad * 4 + reg, cc = ni * 16 + l16;
                float sv = sacc[ni][reg] * SCALE;
                if (kt * 64 + cc > qi * 64 + r) sv = -1e30f;
                Ss[r * 64 + cc] = sv;
            }
        __syncthreads();
        {
            int r = tid >> 2, j = tid & 3;
            float vals[16], mloc = -1e30f;
#pragma unroll
            for (int c = 0; c < 16; ++c) { vals[c] = Ss[r * 64 + j * 16 + c]; mloc = fmaxf(mloc, vals[c]); }
            mloc = fmaxf(mloc, __shfl_xor(mloc, 1));
            mloc = fmaxf(mloc, __shfl_xor(mloc, 2));
            float mold = mS[r], mnew = fmaxf(mold, mloc), ssum = 0.f;
#pragma unroll
            for (int c = 0; c < 16; ++c) {
                float p = __expf(vals[c] - mnew);
                ssum += p;
                Ps2[r * 64 + j * 16 + c] = (bf16)p;
            }
            ssum += __shfl_xor(ssum, 1);
            ssum += __shfl_xor(ssum, 2);
            if (j == 0) { float alpha = __expf(mold - mnew); mS[r] = mnew; lS[r] = lS[r] * alpha + ssum; aS[r] = alpha; }
        }
        __syncthreads();
        {
            float al2[4];
#pragma unroll
            for (int reg = 0; reg < 4; ++reg) al2[reg] = aS[wave * 16 + quad * 4 + reg];
#pragma unroll
            for (int ni = 0; ni < 8; ++ni)
#pragma unroll
                for (int reg = 0; reg < 4; ++reg) o_acc[ni][reg] *= al2[reg];
#pragma unroll
            for (int ks = 0; ks < 2; ++ks) {
                bf16x8 a = *(const bf16x8*)&Ps2[(wave * 16 + l16) * 64 + ks * 32 + quad * 8];
#pragma unroll
                for (int ni = 0; ni < 8; ++ni) {
                    bf16x8 b = *(const bf16x8*)&Vt2[(ni * 16 + l16) * 80 + ks * 32 + quad * 8];
                    o_acc[ni] = __builtin_amdgcn_mfma_f32_16x16x32_bf16(a, b, o_acc[ni], 0, 0, 0);
                }
            }
        }
        __syncthreads();
    }
    {
        float linv[4];
#pragma unroll
        for (int reg = 0; reg < 4; ++reg) linv[reg] = 1.f / fmaxf(lS[wave * 16 + quad * 4 + reg], 1e-20f);
#pragma unroll
        for (int ni = 0; ni < 8; ++ni)
#pragma unroll
            for (int reg = 0; reg < 4; ++reg) {
                int r = wave * 16 + quad * 4 + reg;
                obuf[(size_t)(qi * 64 + r) * HID + hh * HD + ni * 16 + l16] = (bf16)(o_acc[ni][reg] * linv[reg]);
            }
    }
}

// ---------------------------------------------------------------------------
extern "C" void kernel_launch(void* const* d_in, const int* in_sizes, int n_in,
                              void* d_out, int out_size, void* d_ws, size_t ws_size,
                              hipStream_t stream) {
    const float* x   = (const float*)d_in[0];
    const float* Wq  = (const float*)d_in[1];
    const float* bq  = (const float*)d_in[2];
    const float* Wk  = (const float*)d_in[3];
    const float* bk  = (const float*)d_in[4];
    const float* Wv  = (const float*)d_in[5];
    const float* bv  = (const float*)d_in[6];
    const float* Wo  = (const float*)d_in[7];
    const float* bo  = (const float*)d_in[8];
    const float* qg  = (const float*)d_in[9];
    const float* qbt = (const float*)d_in[10];
    const float* kg  = (const float*)d_in[11];
    const float* kbt = (const float*)d_in[12];
    float* out = (float*)d_out;

    // fast-path workspace layout (130,547,712 B):
    //   [0, 16MiB)           : xb  -- later aliased by abuf (attn5 bf16 out)
    //   [16MiB, 64MiB)       : Wqkv
    //   [64MiB, 96MiB)       : Wob
    //   [96MiB, 120MiB)      : qkv
    //   [120MiB, 124MiB)     : vT
    const size_t NEED = 130547712;
    if (ws_size >= NEED) {
        char* p = (char*)d_ws;
        bf16*  xb   = (bf16*)p;
        bf16*  Wqkv = (bf16*)(p + 16777216);
        bf16*  abuf = (bf16*)p;                        // aliases xb (dead after QKV gemm)
        bf16*  Wob  = (bf16*)(p + 67108864);
        bf16*  qkv  = (bf16*)(p + 100663296);
        bf16*  vT   = (bf16*)(p + 125829120);

        // fused fp32 -> bf16 of all inputs (one launch)
        cvt5<<<24576, 256, 0, stream>>>(x, Wq, Wk, Wv, Wo, xb, Wqkv, Wob);

        // fused QKV projection: [2048 x 6144], m201-exact 256x256 quadrant schedule
        gemmQ<1, bf16><<<dim3(24, 8), 512, 0, stream>>>(
            xb, Wqkv, bq, bk, bv, qkv, QSTR, 4096);

        // LN + RoPE in place (q pre-scaled by QSCL)
        ln_rope<<<dim3((S_LEN * (NH + NKV)) / 4), 256, 0, stream>>>(qkv, qg, qbt, kg, kbt);

        // v -> vT
        transpose_v<<<dim3(16, 32), 256, 0, stream>>>(qkv, vT);

        // full-Q attention: 2 blocks/CU, double-buffered K/V, 1 barrier/iter
        attn5<<<dim3(64, 8), 256, 0, stream>>>(qkv, vT, abuf);

        // output projection: 256x128 tiles, proven gemm8 pipeline
        gemm8<256, 128, 4, 2, 0, float><<<dim3(32, 8), 512, 0, stream>>>(
            abuf, Wob, bo, bo, bo, out, 4096, 4096);
    } else {
        char* ws = (char*)d_ws;
        bf16* qbuf = (bf16*)(ws);
        bf16* kbuf = (bf16*)(ws + (16u << 20));
        bf16* vbuf = (bf16*)(ws + (20u << 20));
        bf16* abuf = (bf16*)(ws + (24u << 20));
        gemm_bt<float, bf16><<<dim3(32, 16), 256, 0, stream>>>(x, Wq, bq, qbuf, 4096, 4096);
        gemm_bt<float, bf16><<<dim3(8, 16), 256, 0, stream>>>(x, Wk, bk, kbuf, 1024, 4096);
        gemm_bt<float, bf16><<<dim3(8, 16), 256, 0, stream>>>(x, Wv, bv, vbuf, 1024, 4096);
        ln_rope_f<<<dim3((S_LEN * (NH + NKV)) / 4), 256, 0, stream>>>(qbuf, kbuf, qg, qbt, kg, kbt);
        attn_old<<<dim3(32, 32), 256, 0, stream>>>(qbuf, kbuf, vbuf, abuf);
        gemm_bt<bf16, float><<<dim3(32, 16), 256, 0, stream>>>(abuf, Wo, bo, out, 4096, 4096);
    }
}

// Round 9
// 512.559 us; speedup vs baseline: 1.1146x; 1.1146x over previous
//
#include <hip/hip_runtime.h>

typedef __bf16 bf16;
typedef __bf16 bf16x8 __attribute__((ext_vector_type(8)));
typedef __bf16 bf16x4 __attribute__((ext_vector_type(4)));
typedef float f32x4 __attribute__((ext_vector_type(4)));

#define S_LEN 2048
#define HID 4096
#define NH 32
#define NKV 8
#define HD 128
#define QSTR 6144                      // fused qkv row stride
#define SCALE 0.08838834764831845f
#define QSCL 0.1275164918918885f       // SCALE * log2(e)
#define M2C 16.33f                     // >= 128*QSCL = 16.3221 (Cauchy-Schwarz hard bound)

template <int V> struct IC { static constexpr int value = V; };

__device__ __forceinline__ bf16x8 load8(const bf16* p) { return *(const bf16x8*)p; }
__device__ __forceinline__ bf16x8 load8(const float* p) {
    float4 a = *(const float4*)p;
    float4 b = *(const float4*)(p + 4);
    bf16x8 r;
    r[0] = (bf16)a.x; r[1] = (bf16)a.y; r[2] = (bf16)a.z; r[3] = (bf16)a.w;
    r[4] = (bf16)b.x; r[5] = (bf16)b.y; r[6] = (bf16)b.z; r[7] = (bf16)b.w;
    return r;
}

__device__ __forceinline__ void load_lds16(const bf16* g, bf16* l) {
    __builtin_amdgcn_global_load_lds(
        (const __attribute__((address_space(1))) void*)g,
        (__attribute__((address_space(3))) void*)l, 16, 0, 0);
}

template <int C> __device__ __forceinline__ void vmwait_if() {
    if constexpr (C >= 0) asm volatile("s_waitcnt vmcnt(%0)" ::"n"(C) : "memory");
}

__device__ __forceinline__ void lgkm0() {
    asm volatile("s_waitcnt lgkmcnt(0)" ::: "memory");
    __builtin_amdgcn_sched_barrier(0);
}

// ---------------------------------------------------------------------------
// fused fp32 -> bf16 bulk convert: x | Wq | Wk | Wv -> xb,Wqkv ; Wo -> Wob
// ---------------------------------------------------------------------------
__global__ __launch_bounds__(256) void cvt5(const float* __restrict__ x,
                                            const float* __restrict__ Wq,
                                            const float* __restrict__ Wk,
                                            const float* __restrict__ Wv,
                                            const float* __restrict__ Wo,
                                            bf16* __restrict__ xb,
                                            bf16* __restrict__ Wqkv,
                                            bf16* __restrict__ Wob) {
    int i = blockIdx.x * 256 + threadIdx.x;
    const float* src;
    bf16* dst;
    if (i < 1048576)      { src = x  + (size_t)i * 8;              dst = xb + (size_t)i * 8; }
    else if (i < 3145728) { size_t j = i - 1048576; src = Wq + j * 8; dst = Wqkv + j * 8; }
    else if (i < 3670016) { size_t j = i - 3145728; src = Wk + j * 8; dst = Wqkv + 16777216 + j * 8; }
    else if (i < 4194304) { size_t j = i - 3670016; src = Wv + j * 8; dst = Wqkv + 20971520 + j * 8; }
    else                  { size_t j = i - 4194304; src = Wo + j * 8; dst = Wob + j * 8; }
    *(bf16x8*)dst = load8(src);
}

// ---------------------------------------------------------------------------
// gemm8 (round-2/3 proven, best measured QKV config): 8-phase pipelined GEMM,
// BK=64, double-buffered LDS, counted vmcnt, setprio, granule-XOR swizzle.
// ---------------------------------------------------------------------------
template <int BM, int BN, int WM, int WN, int BMODE, typename TO>
__global__ __launch_bounds__(512, 2) void gemm8(const bf16* __restrict__ A,
                                                const bf16* __restrict__ Bw,
                                                const float* __restrict__ b0,
                                                const float* __restrict__ b1,
                                                const float* __restrict__ b2,
                                                TO* __restrict__ out,
                                                int N, int K) {
    constexpr int RW  = BM / WM;
    constexpr int CW  = BN / WN;
    constexpr int FM  = RW / 16;
    constexpr int FN  = CW / 16;
    constexpr int FMH = FM / 2;
    constexpr int FNH0 = (FN + 1) / 2, FNH1 = FN - FNH0;
    constexpr int SZ0 = FNH0 * 16, SZ1 = FNH1 * 16;
    constexpr int AROWS_H = BM / 2;
    constexpr int B0ROWS = WN * SZ0, B1ROWS = WN * SZ1;
    constexpr int LA  = AROWS_H / 64;
    constexpr int LB0 = B0ROWS / 64, LB1 = B1ROWS / 64;
    constexpr int V0  = 2 * LA + LB0;
    constexpr int V3  = 2 * LA + LB0 + LB1;
    constexpr int V3T = LA + LB1;

    __shared__ __align__(16) bf16 AS[2 * BM * 64];
    __shared__ __align__(16) bf16 BS[2 * BN * 64];

    const int tid  = threadIdx.x;
    const int wave = tid >> 6;
    const int lane = tid & 63;
    const int quad = lane >> 4;
    const int l16  = lane & 15;
    const int wm   = wave / WN;
    const int wn   = wave % WN;

    const int gx   = gridDim.x;
    const int nwg  = gx * gridDim.y;
    const int orig = blockIdx.y * gx + blockIdx.x;
    int wg = orig;
    if ((nwg & 7) == 0) wg = (orig & 7) * (nwg >> 3) + (orig >> 3);
    const int row0 = (wg / gx) * BM;
    const int col0 = (wg % gx) * BN;

    auto stageA = [&](int mh, int bufv, int kt) {
#pragma unroll
        for (int j = 0; j < LA; ++j) {
            int c = j * 512 + tid;
            int r = c >> 3, pg = c & 7;
            int g = pg ^ (r & 7);
            int gr = (r / (RW / 2)) * RW + mh * (RW / 2) + (r % (RW / 2));
            load_lds16(&A[(size_t)(row0 + gr) * K + kt * 64 + g * 8],
                       &AS[bufv * (BM * 64) + mh * (AROWS_H * 64) + c * 8]);
        }
    };
    auto stageB0 = [&](int bufv, int kt) {
#pragma unroll
        for (int j = 0; j < LB0; ++j) {
            int c = j * 512 + tid;
            int r = c >> 3, pg = c & 7;
            int g = pg ^ (r & 7);
            int gc = (r / SZ0) * CW + (r % SZ0);
            load_lds16(&Bw[(size_t)(col0 + gc) * K + kt * 64 + g * 8],
                       &BS[bufv * (BN * 64) + c * 8]);
        }
    };
    auto stageB1 = [&](int bufv, int kt) {
#pragma unroll
        for (int j = 0; j < LB1; ++j) {
            int c = j * 512 + tid;
            int r = c >> 3, pg = c & 7;
            int g = pg ^ (r & 7);
            int gc = (r / SZ1) * CW + SZ0 + (r % SZ1);
            load_lds16(&Bw[(size_t)(col0 + gc) * K + kt * 64 + g * 8],
                       &BS[bufv * (BN * 64) + B0ROWS * 64 + c * 8]);
        }
    };

    f32x4 acc[FM][FN];
#pragma unroll
    for (int mi = 0; mi < FM; ++mi)
#pragma unroll
        for (int ni = 0; ni < FN; ++ni) { f32x4 z = {0.f, 0.f, 0.f, 0.f}; acc[mi][ni] = z; }

    bf16x8 af[FMH][2];
    bf16x8 bfv[FN][2];

    auto loadA = [&](int mh, int bufv) {
#pragma unroll
        for (int mi = 0; mi < FMH; ++mi)
#pragma unroll
            for (int ks = 0; ks < 2; ++ks) {
                int r = wm * (RW / 2) + mi * 16 + l16;
                int g = ks * 4 + quad;
                af[mi][ks] = *(const bf16x8*)&AS[bufv * (BM * 64) + mh * (AROWS_H * 64) +
                                                 r * 64 + ((g ^ (r & 7)) << 3)];
            }
    };
    auto loadB = [&](auto cNH, int bufv) {
        constexpr int NHv = decltype(cNH)::value;
        constexpr int CNT = NHv ? FNH1 : FNH0;
        constexpr int SZ  = NHv ? SZ1 : SZ0;
#pragma unroll
        for (int nj = 0; nj < CNT; ++nj)
#pragma unroll
            for (int ks = 0; ks < 2; ++ks) {
                int r = wn * SZ + nj * 16 + l16;
                int g = ks * 4 + quad;
                bfv[NHv * FNH0 + nj][ks] =
                    *(const bf16x8*)&BS[bufv * (BN * 64) + NHv * (B0ROWS * 64) +
                                        r * 64 + ((g ^ (r & 7)) << 3)];
            }
    };
    auto mmac = [&](auto cMH, auto cNH) {
        constexpr int MH = decltype(cMH)::value, NHv = decltype(cNH)::value;
        constexpr int NB = NHv ? FNH0 : 0, NE = NHv ? FN : FNH0;
        __builtin_amdgcn_s_setprio(1);
#pragma unroll
        for (int mi = 0; mi < FMH; ++mi)
#pragma unroll
            for (int ni = NB; ni < NE; ++ni)
#pragma unroll
                for (int ks = 0; ks < 2; ++ks)
                    acc[MH * FMH + mi][ni] = __builtin_amdgcn_mfma_f32_16x16x32_bf16(
                        af[mi][ks], bfv[ni][ks], acc[MH * FMH + mi][ni], 0, 0, 0);
        __builtin_amdgcn_s_setprio(0);
    };

    auto run_tile = [&](int t, auto cSA1, auto cSB1, auto cSA0, auto cSB0,
                        auto cV0, auto cV3) {
        const int buf = t & 1, nbuf = buf ^ 1;
        loadA(0, buf);
        loadB(IC<0>{}, buf);
        if constexpr (decltype(cSA1)::value) stageA(1, nbuf, t + 1);
        __builtin_amdgcn_s_barrier();
        lgkm0();
        mmac(IC<0>{}, IC<0>{});
        vmwait_if<decltype(cV0)::value>();
        __builtin_amdgcn_s_barrier();
        loadB(IC<1>{}, buf);
        if constexpr (decltype(cSB1)::value) stageB1(nbuf, t + 1);
        __builtin_amdgcn_s_barrier();
        lgkm0();
        mmac(IC<0>{}, IC<1>{});
        __builtin_amdgcn_s_barrier();
        loadA(1, buf);
        if constexpr (decltype(cSA0)::value) stageA(0, buf, t + 2);
        __builtin_amdgcn_s_barrier();
        lgkm0();
        mmac(IC<1>{}, IC<0>{});
        __builtin_amdgcn_s_barrier();
        if constexpr (decltype(cSB0)::value) stageB0(buf, t + 2);
        __builtin_amdgcn_s_barrier();
        lgkm0();
        mmac(IC<1>{}, IC<1>{});
        vmwait_if<decltype(cV3)::value>();
        __builtin_amdgcn_s_barrier();
    };

    stageA(0, 0, 0); stageB0(0, 0);
    stageA(1, 0, 0); stageB1(0, 0);
    stageA(0, 1, 1); stageB0(1, 1);
    vmwait_if<V3>();
    __builtin_amdgcn_s_barrier();

    const int NT = K >> 6;
    for (int t = 0; t < NT - 2; ++t)
        run_tile(t, IC<1>{}, IC<1>{}, IC<1>{}, IC<1>{}, IC<V0>{}, IC<V3>{});
    run_tile(NT - 2, IC<1>{}, IC<1>{}, IC<0>{}, IC<0>{}, IC<V0>{}, IC<V3T>{});
    run_tile(NT - 1, IC<0>{}, IC<0>{}, IC<0>{}, IC<0>{}, IC<0>{}, IC<-1>{});

#pragma unroll
    for (int ni = 0; ni < FN; ++ni) {
        int n = col0 + wn * CW + ni * 16 + l16;
        float bv;
        if (BMODE == 0) bv = b0[n];
        else bv = (n < 4096) ? b0[n] : ((n < 5120) ? b1[n - 4096] : b2[n - 5120]);
#pragma unroll
        for (int mi = 0; mi < FM; ++mi) {
            int m = row0 + wm * RW + mi * 16 + quad * 4;
#pragma unroll
            for (int reg = 0; reg < 4; ++reg)
                out[(size_t)(m + reg) * N + n] = (TO)(acc[mi][ni][reg] + bv);
        }
    }
}

// ---------------------------------------------------------------------------
// LayerNorm(HD=128) + RoPE in place on fused qkv buffer (stride QSTR).
// ---------------------------------------------------------------------------
__global__ __launch_bounds__(256) void ln_rope(bf16* __restrict__ qkv,
                                               const float* __restrict__ qg, const float* __restrict__ qbt,
                                               const float* __restrict__ kg, const float* __restrict__ kbt) {
    int row  = blockIdx.x * 4 + (threadIdx.x >> 6);
    int lane = threadIdx.x & 63;

    bf16* ptr;
    const float *g, *bb;
    int s;
    float osc;
    if (row < S_LEN * NH) {
        s   = row >> 5;
        ptr = qkv + (size_t)s * QSTR + (row & 31) * HD;
        g   = qg; bb = qbt; osc = QSCL;
    } else {
        int r2 = row - S_LEN * NH;
        s   = r2 >> 3;
        ptr = qkv + (size_t)s * QSTR + 4096 + (r2 & 7) * HD;
        g   = kg; bb = kbt; osc = 1.f;
    }

    float x1 = (float)ptr[lane];
    float x2 = (float)ptr[lane + 64];
    float sum = x1 + x2;
    float sq  = x1 * x1 + x2 * x2;
#pragma unroll
    for (int m = 1; m < 64; m <<= 1) {
        sum += __shfl_xor(sum, m);
        sq  += __shfl_xor(sq, m);
    }
    float mu  = sum * (1.f / 128.f);
    float var = sq * (1.f / 128.f) - mu * mu;
    float rs  = rsqrtf(var + 1e-5f);
    float n1  = (x1 - mu) * rs * g[lane] + bb[lane];
    float n2  = (x2 - mu) * rs * g[lane + 64] + bb[lane + 64];

    float inv = exp2f(-0.2958057514f * (float)lane);
    float ang = (float)s * inv;
    float sn, cs;
    sincosf(ang, &sn, &cs);

    ptr[lane]      = (bf16)((n1 * cs - n2 * sn) * osc);
    ptr[lane + 64] = (bf16)((n2 * cs + n1 * sn) * osc);
}

// ---------------------------------------------------------------------------
// Transpose v (cols 5120..6143 of qkv, [s][c]) -> vT [c][s].
// ---------------------------------------------------------------------------
__global__ __launch_bounds__(256) void transpose_v(const bf16* __restrict__ qkv,
                                                   bf16* __restrict__ vT) {
    __shared__ bf16 Ts[64 * 64];
    const int c0 = blockIdx.x * 64;
    const int s0 = blockIdx.y * 64;
    const int tid = threadIdx.x;

#pragma unroll
    for (int i = 0; i < 2; ++i) {
        int cc = i * 256 + tid;
        int r = cc >> 3, col8 = cc & 7;
        *(bf16x8*)&Ts[r * 64 + ((col8 ^ (r & 7)) << 3)] =
            *(const bf16x8*)&qkv[(size_t)(s0 + r) * QSTR + 5120 + c0 + (col8 << 3)];
    }
    __syncthreads();
#pragma unroll
    for (int i = 0; i < 2; ++i) {
        int oc = i * 256 + tid;
        int c = oc & 63, sb = oc >> 6;
        bf16x8 r8;
#pragma unroll
        for (int j = 0; j < 8; ++j) {
            int sg = sb * 8 + j;
            r8[j] = Ts[sg * 64 + ((((c >> 3) ^ (sg & 7)) << 3) + (c & 7))];
        }
        *(bf16x8*)&vT[(size_t)(c0 + c) * S_LEN + s0 + sb * 8] = r8;
    }
}

// ---------------------------------------------------------------------------
// Flash attention v6: attn4's split-parity structure (8 waves = 4 heads x
// 2 kt-parities, in-LDS merge) with ASYNC gload_lds staging + counted vmcnt
// (the proven gemm8 idiom: pre-swizzled global src, linear LDS dest,
// swizzled ds_read). K double-buffered (4 tiles), V single-buffered
// (2 tiles), Ps per-wave. LDS = 128 KiB exactly. Per iter:
//   issue V(it) [4 loads], issue K(it+1) [4 loads] -> vmwait(8) [K(it)
//   retired; 8 newer fly] -> barrier -> QK+softmax -> vmwait(4) [V(it)
//   retired; K(it+1) newer] -> barrier -> PV -> barrier.
// Tail iteration uses vmwait(4)/vmwait(0). All WAR/RAW barrier-separated.
// ---------------------------------------------------------------------------
__global__ __launch_bounds__(512) void attn6(const bf16* __restrict__ qkv,
                                             const bf16* __restrict__ vT,
                                             bf16* __restrict__ abuf) {
    const int pairp = blockIdx.x;
    const int kvh   = blockIdx.y;
    const int tid   = threadIdx.x;
    const int wave  = tid >> 6;
    const int lane  = tid & 63;
    const int quad  = lane >> 4;
    const int l16   = lane & 15;
    const int spw   = wave >> 2;       // kt parity this wave handles
    const int hw    = wave & 3;        // head within kv group
    const int h     = kvh * 4 + hw;

    // LDS: K[2buf][2tp][64*128] | V[2tp][128*64] | Ps[8][32*64] = 128 KiB
    __shared__ __align__(16) bf16 smem[4 * 8192 + 2 * 8192 + 8 * 2048];
    bf16* Ksb = smem;                  // slot (kbuf*2+tp)*8192
    bf16* Vtb = smem + 4 * 8192;       // slot tp*8192
    bf16* Psb = smem + 6 * 8192;       // per-wave stride 2048

    bf16x8 onesf;
#pragma unroll
    for (int j = 0; j < 8; ++j) onesf[j] = (bf16)1.f;

    // stage pair pr's K tiles (2pr, 2pr+1) into kbuf kb (async, pre-swizzled)
    auto stageK = [&](int pr, int kb) {
#pragma unroll
        for (int j = 0; j < 4; ++j) {
            int c = j * 512 + tid;
            int tile = c >> 10, cc = c & 1023;
            int key = cc >> 4, pg = cc & 15;
            int g = pg ^ (key & 7);
            load_lds16(&qkv[(size_t)((2 * pr + tile) * 64 + key) * QSTR + 4096 +
                            kvh * HD + g * 8],
                       &Ksb[(kb * 2 + tile) * 8192 + cc * 8]);
        }
    };
    auto stageV = [&](int pr) {
#pragma unroll
        for (int j = 0; j < 4; ++j) {
            int c = j * 512 + tid;
            int tile = c >> 10, cc = c & 1023;
            int d = cc >> 3, pg = cc & 7;
            int g = pg ^ (d & 7);
            load_lds16(&vT[(size_t)(kvh * HD + d) * S_LEN + (2 * pr + tile) * 64 + g * 8],
                       &Vtb[tile * 8192 + cc * 8]);
        }
    };

    for (int ph = 0; ph < 2; ++ph) {
        const int qt  = ph ? (63 - pairp) : pairp;
        const int r0  = qt * 32;
        const int nkt = qt / 2 + 1;
        const int nit = (nkt + 1) >> 1;    // K/V tile PAIRS

        // Q fragments (already scaled by QSCL in ln_rope)
        bf16x8 qf[2][4];
#pragma unroll
        for (int mi = 0; mi < 2; ++mi)
#pragma unroll
            for (int ks = 0; ks < 4; ++ks)
                qf[mi][ks] = *(const bf16x8*)&qkv[(size_t)(r0 + mi * 16 + l16) * QSTR +
                                                  h * HD + ks * 32 + quad * 8];

        f32x4 o_acc[2][8];
#pragma unroll
        for (int mi = 0; mi < 2; ++mi)
#pragma unroll
            for (int ni = 0; ni < 8; ++ni) {
                f32x4 z = {0.f, 0.f, 0.f, 0.f};
                o_acc[mi][ni] = z;
            }
        f32x4 lacc[2];
#pragma unroll
        for (int mi = 0; mi < 2; ++mi) { f32x4 z = {0.f, 0.f, 0.f, 0.f}; lacc[mi] = z; }

        stageK(0, 0);                     // prologue: K pair 0 -> kbuf 0

        for (int it = 0; it < nit; ++it) {
            const int kb = it & 1;
            // issue V(it) first (older), then K(it+1) (newer): the counted
            // waits below rely on this order.
            stageV(it);
            if (it + 1 < nit) { stageK(it + 1, kb ^ 1); vmwait_if<8>(); }
            else              { vmwait_if<4>(); }
            __syncthreads();              // K(it) visible to all

            const int kt = 2 * it + spw;
            const bf16* Kw = Ksb + (kb * 2 + spw) * 8192;
            const bf16* Vw = Vtb + spw * 8192;
            bf16* Pw = Psb + wave * 2048;

            if (kt < nkt) {
                // S = Q K^T (log2-scaled)
                f32x4 sacc[2][4];
#pragma unroll
                for (int mi = 0; mi < 2; ++mi)
#pragma unroll
                    for (int ni = 0; ni < 4; ++ni) {
                        f32x4 z = {0.f, 0.f, 0.f, 0.f};
                        sacc[mi][ni] = z;
                    }
                __builtin_amdgcn_s_setprio(1);
#pragma unroll
                for (int ks = 0; ks < 4; ++ks)
#pragma unroll
                    for (int ni = 0; ni < 4; ++ni) {
                        bf16x8 kf = *(const bf16x8*)&Kw[(ni * 16 + l16) * 128 +
                                                        ((((ks << 2) + quad) ^ (l16 & 7)) << 3)];
                        sacc[0][ni] = __builtin_amdgcn_mfma_f32_16x16x32_bf16(qf[0][ks], kf, sacc[0][ni], 0, 0, 0);
                        sacc[1][ni] = __builtin_amdgcn_mfma_f32_16x16x32_bf16(qf[1][ks], kf, sacc[1][ni], 0, 0, 0);
                    }
                __builtin_amdgcn_s_setprio(0);

                // fixed-max softmax: p = exp2(s2 - M2C); masked -> 0
#pragma unroll
                for (int mi = 0; mi < 2; ++mi)
#pragma unroll
                    for (int reg = 0; reg < 4; ++reg) {
                        int rloc = mi * 16 + quad * 4 + reg;
                        int qrow = r0 + rloc;
#pragma unroll
                        for (int ni = 0; ni < 4; ++ni) {
                            int key = kt * 64 + ni * 16 + l16;
                            float t = (key > qrow) ? -1e30f : (sacc[mi][ni][reg] - M2C);
                            float p = exp2f(t);
                            int blk = (ni * 2 + (l16 >> 3)) ^ (rloc & 7);
                            Pw[rloc * 64 + blk * 8 + (l16 & 7)] = (bf16)p;
                        }
                    }
            }

            if (it + 1 < nit) vmwait_if<4>();   // V(it) retired (K(it+1) newer)
            else              vmwait_if<0>();
            __syncthreads();              // V(it) visible to all

            if (kt < nkt) {
                const bf16* Vw2 = Vw;
                bf16* Pw2 = Pw;
                // O += P @ V ; l += P @ ones
                __builtin_amdgcn_s_setprio(1);
#pragma unroll
                for (int ks2 = 0; ks2 < 2; ++ks2) {
                    bf16x8 pa[2];
#pragma unroll
                    for (int mi = 0; mi < 2; ++mi) {
                        int rloc = mi * 16 + l16;
                        pa[mi] = *(const bf16x8*)&Pw2[rloc * 64 +
                                                      ((((ks2 << 2) + quad) ^ (rloc & 7)) << 3)];
                    }
#pragma unroll
                    for (int ni = 0; ni < 8; ++ni) {
                        int d = ni * 16 + l16;
                        bf16x8 vf = *(const bf16x8*)&Vw2[d * 64 + ((((ks2 << 2) + quad) ^ (d & 7)) << 3)];
                        o_acc[0][ni] = __builtin_amdgcn_mfma_f32_16x16x32_bf16(pa[0], vf, o_acc[0][ni], 0, 0, 0);
                        o_acc[1][ni] = __builtin_amdgcn_mfma_f32_16x16x32_bf16(pa[1], vf, o_acc[1][ni], 0, 0, 0);
                    }
                    lacc[0] = __builtin_amdgcn_mfma_f32_16x16x32_bf16(pa[0], onesf, lacc[0], 0, 0, 0);
                    lacc[1] = __builtin_amdgcn_mfma_f32_16x16x32_bf16(pa[1], onesf, lacc[1], 0, 0, 0);
                }
                __builtin_amdgcn_s_setprio(0);
            }
            __syncthreads();              // PV done before next stageV/stageK
        }

        // cross-parity merge via LDS (K region = 64 KiB fp32 scratch; Ls in V region)
        float* M  = (float*)smem;                    // 16384 floats = K region
        float* Ls = (float*)&smem[4 * 8192];         // V region (free now)
        if (spw == 1) {
            float* Mw = M + hw * 4096;
#pragma unroll
            for (int mi = 0; mi < 2; ++mi)
#pragma unroll
                for (int ni = 0; ni < 8; ++ni)
#pragma unroll
                    for (int j = 0; j < 4; ++j)
                        Mw[((mi * 8 + ni) * 4 + j) * 64 + lane] = o_acc[mi][ni][j];
            if (l16 == 0)
#pragma unroll
                for (int mi = 0; mi < 2; ++mi)
#pragma unroll
                    for (int reg = 0; reg < 4; ++reg)
                        Ls[hw * 32 + mi * 16 + quad * 4 + reg] = lacc[mi][reg];
        }
        __syncthreads();
        if (spw == 0) {
            float* Mw = M + hw * 4096;
#pragma unroll
            for (int mi = 0; mi < 2; ++mi) {
                float linv[4];
#pragma unroll
                for (int reg = 0; reg < 4; ++reg)
                    linv[reg] = 1.f / fmaxf(lacc[mi][reg] +
                                            Ls[hw * 32 + mi * 16 + quad * 4 + reg], 1e-30f);
#pragma unroll
                for (int ni = 0; ni < 8; ++ni)
#pragma unroll
                    for (int reg = 0; reg < 4; ++reg) {
                        float v = o_acc[mi][ni][reg] + Mw[((mi * 8 + ni) * 4 + reg) * 64 + lane];
                        int s = r0 + mi * 16 + quad * 4 + reg;
                        abuf[(size_t)s * HID + h * HD + ni * 16 + l16] = (bf16)(v * linv[reg]);
                    }
            }
        }
        __syncthreads();
    }
}

// ===========================================================================
// Fallback path — only if workspace is unexpectedly small.
// ===========================================================================
template <typename TA, typename TO>
__global__ __launch_bounds__(256) void gemm_bt(const TA* __restrict__ A,
                                               const float* __restrict__ W,
                                               const float* __restrict__ bias,
                                               TO* __restrict__ out,
                                               int N, int K) {
    __shared__ __align__(16) bf16 As[128 * 64];
    __shared__ __align__(16) bf16 Bs[128 * 64];
    const int tid = threadIdx.x, wave = tid >> 6, lane = tid & 63;
    const int quad = lane >> 4, l16 = lane & 15, wm = wave >> 1, wn = wave & 1;
    const int row0 = blockIdx.y * 128, col0 = blockIdx.x * 128;
    f32x4 acc[4][4];
#pragma unroll
    for (int mi = 0; mi < 4; ++mi)
#pragma unroll
        for (int ni = 0; ni < 4; ++ni) { f32x4 z = {0.f,0.f,0.f,0.f}; acc[mi][ni] = z; }
    for (int k0 = 0; k0 < K; k0 += 64) {
#pragma unroll
        for (int i = 0; i < 4; ++i) {
            int c = i * 256 + tid, r = c >> 3, col8 = (c & 7) << 3;
            *(bf16x8*)&As[r * 64 + col8] = load8(&A[(size_t)(row0 + r) * K + k0 + col8]);
            *(bf16x8*)&Bs[r * 64 + col8] = load8(&W[(size_t)(col0 + r) * K + k0 + col8]);
        }
        __syncthreads();
#pragma unroll
        for (int ks = 0; ks < 2; ++ks) {
            bf16x8 af[4], bfr[4];
#pragma unroll
            for (int mi = 0; mi < 4; ++mi)
                af[mi] = *(const bf16x8*)&As[(wm * 64 + mi * 16 + l16) * 64 + ks * 32 + quad * 8];
#pragma unroll
            for (int ni = 0; ni < 4; ++ni)
                bfr[ni] = *(const bf16x8*)&Bs[(wn * 64 + ni * 16 + l16) * 64 + ks * 32 + quad * 8];
#pragma unroll
            for (int mi = 0; mi < 4; ++mi)
#pragma unroll
                for (int ni = 0; ni < 4; ++ni)
                    acc[mi][ni] = __builtin_amdgcn_mfma_f32_16x16x32_bf16(af[mi], bfr[ni], acc[mi][ni], 0, 0, 0);
        }
        __syncthreads();
    }
#pragma unroll
    for (int ni = 0; ni < 4; ++ni) {
        int n = col0 + wn * 64 + ni * 16 + l16;
        float bv = bias[n];
#pragma unroll
        for (int mi = 0; mi < 4; ++mi) {
            int m = row0 + wm * 64 + mi * 16 + quad * 4;
#pragma unroll
            for (int reg = 0; reg < 4; ++reg)
                out[(size_t)(m + reg) * N + n] = (TO)(acc[mi][ni][reg] + bv);
        }
    }
}

__global__ __launch_bounds__(256) void ln_rope_f(bf16* __restrict__ qb, bf16* __restrict__ kb,
                                                 const float* __restrict__ qg, const float* __restrict__ qbt,
                                                 const float* __restrict__ kg, const float* __restrict__ kbt) {
    int row = blockIdx.x * 4 + (threadIdx.x >> 6);
    int lane = threadIdx.x & 63;
    bf16* ptr; const float *g, *bb; int s;
    if (row < S_LEN * NH) { s = row >> 5; ptr = qb + (size_t)s * (NH * HD) + (row & 31) * HD; g = qg; bb = qbt; }
    else { int r2 = row - S_LEN * NH; s = r2 >> 3; ptr = kb + (size_t)s * (NKV * HD) + (r2 & 7) * HD; g = kg; bb = kbt; }
    float x1 = (float)ptr[lane], x2 = (float)ptr[lane + 64];
    float sum = x1 + x2, sq = x1 * x1 + x2 * x2;
#pragma unroll
    for (int m = 1; m < 64; m <<= 1) { sum += __shfl_xor(sum, m); sq += __shfl_xor(sq, m); }
    float mu = sum * (1.f / 128.f), var = sq * (1.f / 128.f) - mu * mu;
    float rs = rsqrtf(var + 1e-5f);
    float n1 = (x1 - mu) * rs * g[lane] + bb[lane];
    float n2 = (x2 - mu) * rs * g[lane + 64] + bb[lane + 64];
    float inv = powf(500000.f, -(float)lane * (1.f / 64.f));
    float ang = (float)s * inv, sn, cs;
    sincosf(ang, &sn, &cs);
    ptr[lane] = (bf16)(n1 * cs - n2 * sn);
    ptr[lane + 64] = (bf16)(n2 * cs + n1 * sn);
}

__global__ __launch_bounds__(256) void attn_old(const bf16* __restrict__ qbuf,
                                                const bf16* __restrict__ kbuf,
                                                const bf16* __restrict__ vbuf,
                                                bf16* __restrict__ obuf) {
    const int qi = blockIdx.x, hh = blockIdx.y, kvh = hh >> 2;
    __shared__ __align__(16) bf16 Qs[64 * 128];
    __shared__ __align__(16) bf16 Ks2[64 * 128];
    __shared__ __align__(16) bf16 Vt2[128 * 80];
    __shared__ __align__(16) float Ss[64 * 64];
    __shared__ __align__(16) bf16 Ps2[64 * 64];
    __shared__ float mS[64], lS[64], aS[64];
    const int tid = threadIdx.x, wave = tid >> 6, lane = tid & 63;
    const int quad = lane >> 4, l16 = lane & 15;
#pragma unroll
    for (int i = 0; i < 4; ++i) {
        int c = i * 256 + tid, r = c >> 4, col8 = (c & 15) << 3;
        *(int4*)&Qs[r * 128 + col8] = *(const int4*)&qbuf[(size_t)(qi * 64 + r) * HID + hh * HD + col8];
    }
    if (tid < 64) { mS[tid] = -1e30f; lS[tid] = 0.f; }
    f32x4 o_acc[8];
#pragma unroll
    for (int i = 0; i < 8; ++i) { f32x4 z = {0.f,0.f,0.f,0.f}; o_acc[i] = z; }
    __syncthreads();
    for (int kt = 0; kt <= qi; ++kt) {
#pragma unroll
        for (int i = 0; i < 4; ++i) {
            int c = i * 256 + tid, r = c >> 4, col8 = (c & 15) << 3;
            const size_t gofs = (size_t)(kt * 64 + r) * (NKV * HD) + kvh * HD + col8;
            *(int4*)&Ks2[r * 128 + col8] = *(const int4*)&kbuf[gofs];
            bf16x8 vv = *(const bf16x8*)&vbuf[gofs];
#pragma unroll
            for (int e = 0; e < 8; ++e) Vt2[(col8 + e) * 80 + r] = vv[e];
        }
        __syncthreads();
        f32x4 sacc[4];
#pragma unroll
        for (int ni = 0; ni < 4; ++ni) { f32x4 z = {0.f,0.f,0.f,0.f}; sacc[ni] = z; }
#pragma unroll
        for (int ks = 0; ks < 4; ++ks) {
            bf16x8 a = *(const bf16x8*)&Qs[(wave * 16 + l16) * 128 + ks * 32 + quad * 8];
#pragma unroll
            for (int ni = 0; ni < 4; ++ni) {
                bf16x8 b = *(const bf16x8*)&Ks2[(ni * 16 + l16) * 128 + ks * 32 + quad * 8];
                sacc[ni] = __builtin_amdgcn_mfma_f32_16x16x32_bf16(a, b, sacc[ni], 0, 0, 0);
            }
        }
#pragma unroll
        for (int ni = 0; ni < 4; ++ni)
#pragma unroll
            for (int reg = 0; reg < 4; ++reg) {
                int r = wave * 16 + quad * 4 + reg, cc = ni * 16 + l16;
                float sv = sacc[ni][reg] * SCALE;
                if (kt * 64 + cc > qi * 64 + r) sv = -1e30f;
                Ss[r * 64 + cc] = sv;
            }
        __syncthreads();
        {
            int r = tid >> 2, j = tid & 3;
            float vals[16], mloc = -1e30f;
#pragma unroll
            for (int c = 0; c < 16; ++c) { vals[c] = Ss[r * 64 + j * 16 + c]; mloc = fmaxf(mloc, vals[c]); }
            mloc = fmaxf(mloc, __shfl_xor(mloc, 1));
            mloc = fmaxf(mloc, __shfl_xor(mloc, 2));
            float mold = mS[r], mnew = fmaxf(mold, mloc), ssum = 0.f;
#pragma unroll
            for (int c = 0; c < 16; ++c) {
                float p = __expf(vals[c] - mnew);
                ssum += p;
                Ps2[r * 64 + j * 16 + c] = (bf16)p;
            }
            ssum += __shfl_xor(ssum, 1);
            ssum += __shfl_xor(ssum, 2);
            if (j == 0) { float alpha = __expf(mold - mnew); mS[r] = mnew; lS[r] = lS[r] * alpha + ssum; aS[r] = alpha; }
        }
        __syncthreads();
        {
            float al2[4];
#pragma unroll
            for (int reg = 0; reg < 4; ++reg) al2[reg] = aS[wave * 16 + quad * 4 + reg];
#pragma unroll
            for (int ni = 0; ni < 8; ++ni)
#pragma unroll
                for (int reg = 0; reg < 4; ++reg) o_acc[ni][reg] *= al2[reg];
#pragma unroll
            for (int ks = 0; ks < 2; ++ks) {
                bf16x8 a = *(const bf16x8*)&Ps2[(wave * 16 + l16) * 64 + ks * 32 + quad * 8];
#pragma unroll
                for (int ni = 0; ni < 8; ++ni) {
                    bf16x8 b = *(const bf16x8*)&Vt2[(ni * 16 + l16) * 80 + ks * 32 + quad * 8];
                    o_acc[ni] = __builtin_amdgcn_mfma_f32_16x16x32_bf16(a, b, o_acc[ni], 0, 0, 0);
                }
            }
        }
        __syncthreads();
    }
    {
        float linv[4];
#pragma unroll
        for (int reg = 0; reg < 4; ++reg) linv[reg] = 1.f / fmaxf(lS[wave * 16 + quad * 4 + reg], 1e-20f);
#pragma unroll
        for (int ni = 0; ni < 8; ++ni)
#pragma unroll
            for (int reg = 0; reg < 4; ++reg) {
                int r = wave * 16 + quad * 4 + reg;
                obuf[(size_t)(qi * 64 + r) * HID + hh * HD + ni * 16 + l16] = (bf16)(o_acc[ni][reg] * linv[reg]);
            }
    }
}

// ---------------------------------------------------------------------------
extern "C" void kernel_launch(void* const* d_in, const int* in_sizes, int n_in,
                              void* d_out, int out_size, void* d_ws, size_t ws_size,
                              hipStream_t stream) {
    const float* x   = (const float*)d_in[0];
    const float* Wq  = (const float*)d_in[1];
    const float* bq  = (const float*)d_in[2];
    const float* Wk  = (const float*)d_in[3];
    const float* bk  = (const float*)d_in[4];
    const float* Wv  = (const float*)d_in[5];
    const float* bv  = (const float*)d_in[6];
    const float* Wo  = (const float*)d_in[7];
    const float* bo  = (const float*)d_in[8];
    const float* qg  = (const float*)d_in[9];
    const float* qbt = (const float*)d_in[10];
    const float* kg  = (const float*)d_in[11];
    const float* kbt = (const float*)d_in[12];
    float* out = (float*)d_out;

    // fast-path workspace layout (130,547,712 B):
    //   [0, 16MiB)           : xb  -- later aliased by abuf (attn6 bf16 out)
    //   [16MiB, 64MiB)       : Wqkv
    //   [64MiB, 96MiB)       : Wob
    //   [96MiB, 120MiB)      : qkv
    //   [120MiB, 124MiB)     : vT
    const size_t NEED = 130547712;
    if (ws_size >= NEED) {
        char* p = (char*)d_ws;
        bf16*  xb   = (bf16*)p;
        bf16*  Wqkv = (bf16*)(p + 16777216);
        bf16*  abuf = (bf16*)p;                        // aliases xb (dead after QKV gemm)
        bf16*  Wob  = (bf16*)(p + 67108864);
        bf16*  qkv  = (bf16*)(p + 100663296);
        bf16*  vT   = (bf16*)(p + 125829120);

        // fused fp32 -> bf16 of all inputs (one launch)
        cvt5<<<24576, 256, 0, stream>>>(x, Wq, Wk, Wv, Wo, xb, Wqkv, Wob);

        // fused QKV projection: [2048 x 6144], 256x192 tiles (full 256-block
        // grid) -- best measured config (round 3: 126-129 us)
        gemm8<256, 192, 2, 4, 1, bf16><<<dim3(32, 8), 512, 0, stream>>>(
            xb, Wqkv, bq, bk, bv, qkv, QSTR, 4096);

        // LN + RoPE in place (q pre-scaled by QSCL)
        ln_rope<<<dim3((S_LEN * (NH + NKV)) / 4), 256, 0, stream>>>(qkv, qg, qbt, kg, kbt);

        // v -> vT
        transpose_v<<<dim3(16, 32), 256, 0, stream>>>(qkv, vT);

        // split-parity attention with async gload_lds staging + counted vmcnt
        attn6<<<dim3(32, 8), 512, 0, stream>>>(qkv, vT, abuf);

        // output projection: 256x128 tiles, proven gemm8 pipeline
        gemm8<256, 128, 4, 2, 0, float><<<dim3(32, 8), 512, 0, stream>>>(
            abuf, Wob, bo, bo, bo, out, 4096, 4096);
    } else {
        char* ws = (char*)d_ws;
        bf16* qbuf = (bf16*)(ws);
        bf16* kbuf = (bf16*)(ws + (16u << 20));
        bf16* vbuf = (bf16*)(ws + (20u << 20));
        bf16* abuf = (bf16*)(ws + (24u << 20));
        gemm_bt<float, bf16><<<dim3(32, 16), 256, 0, stream>>>(x, Wq, bq, qbuf, 4096, 4096);
        gemm_bt<float, bf16><<<dim3(8, 16), 256, 0, stream>>>(x, Wk, bk, kbuf, 1024, 4096);
        gemm_bt<float, bf16><<<dim3(8, 16), 256, 0, stream>>>(x, Wv, bv, vbuf, 1024, 4096);
        ln_rope_f<<<dim3((S_LEN * (NH + NKV)) / 4), 256, 0, stream>>>(qbuf, kbuf, qg, qbt, kg, kbt);
        attn_old<<<dim3(32, 32), 256, 0, stream>>>(qbuf, kbuf, vbuf, abuf);
        gemm_bt<bf16, float><<<dim3(32, 16), 256, 0, stream>>>(abuf, Wo, bo, out, 4096, 4096);
    }
}

// Round 10
// 501.555 us; speedup vs baseline: 1.1390x; 1.0219x over previous
//
#include <hip/hip_runtime.h>

typedef __bf16 bf16;
typedef __bf16 bf16x8 __attribute__((ext_vector_type(8)));
typedef __bf16 bf16x4 __attribute__((ext_vector_type(4)));
typedef float f32x4 __attribute__((ext_vector_type(4)));

#define S_LEN 2048
#define HID 4096
#define NH 32
#define NKV 8
#define HD 128
#define QSTR 6144                      // fused qkv row stride
#define SCALE 0.08838834764831845f
#define QSCL 0.1275164918918885f       // SCALE * log2(e)
#define M2C 16.33f                     // >= 128*QSCL = 16.3221 (Cauchy-Schwarz hard bound)

template <int V> struct IC { static constexpr int value = V; };

__device__ __forceinline__ bf16x8 load8(const bf16* p) { return *(const bf16x8*)p; }
__device__ __forceinline__ bf16x8 load8(const float* p) {
    float4 a = *(const float4*)p;
    float4 b = *(const float4*)(p + 4);
    bf16x8 r;
    r[0] = (bf16)a.x; r[1] = (bf16)a.y; r[2] = (bf16)a.z; r[3] = (bf16)a.w;
    r[4] = (bf16)b.x; r[5] = (bf16)b.y; r[6] = (bf16)b.z; r[7] = (bf16)b.w;
    return r;
}

__device__ __forceinline__ void load_lds16(const bf16* g, bf16* l) {
    __builtin_amdgcn_global_load_lds(
        (const __attribute__((address_space(1))) void*)g,
        (__attribute__((address_space(3))) void*)l, 16, 0, 0);
}

template <int C> __device__ __forceinline__ void vmwait_if() {
    if constexpr (C >= 0) asm volatile("s_waitcnt vmcnt(%0)" ::"n"(C) : "memory");
}

__device__ __forceinline__ void lgkm0() {
    asm volatile("s_waitcnt lgkmcnt(0)" ::: "memory");
    __builtin_amdgcn_sched_barrier(0);
}

// ---------------------------------------------------------------------------
// fused fp32 -> bf16 bulk convert: x | Wq | Wk | Wv -> xb,Wqkv ; Wo -> Wob
// ---------------------------------------------------------------------------
__global__ __launch_bounds__(256) void cvt5(const float* __restrict__ x,
                                            const float* __restrict__ Wq,
                                            const float* __restrict__ Wk,
                                            const float* __restrict__ Wv,
                                            const float* __restrict__ Wo,
                                            bf16* __restrict__ xb,
                                            bf16* __restrict__ Wqkv,
                                            bf16* __restrict__ Wob) {
    int i = blockIdx.x * 256 + threadIdx.x;
    const float* src;
    bf16* dst;
    if (i < 1048576)      { src = x  + (size_t)i * 8;              dst = xb + (size_t)i * 8; }
    else if (i < 3145728) { size_t j = i - 1048576; src = Wq + j * 8; dst = Wqkv + j * 8; }
    else if (i < 3670016) { size_t j = i - 3145728; src = Wk + j * 8; dst = Wqkv + 16777216 + j * 8; }
    else if (i < 4194304) { size_t j = i - 3670016; src = Wv + j * 8; dst = Wqkv + 20971520 + j * 8; }
    else                  { size_t j = i - 4194304; src = Wo + j * 8; dst = Wob + j * 8; }
    *(bf16x8*)dst = load8(src);
}

// ---------------------------------------------------------------------------
// gemm8 (proven): 8-phase pipelined GEMM, BK=64, double-buffered LDS, counted
// vmcnt, setprio, granule-XOR swizzle. NEW: 2D XCD tiling for (32,8) grids --
// each XCD owns a 4-row x 8-col tile of the block grid (bijective:
// xcd=orig&7, idx=orig>>3; row_p=(xcd>>2)*4+(idx>>3), col_p=(xcd&3)*8+(idx&7))
// cutting per-XCD L2 working set 50 MB -> 20 MB (A 8 MB + B 12 MB).
// ---------------------------------------------------------------------------
template <int BM, int BN, int WM, int WN, int BMODE, typename TO>
__global__ __launch_bounds__(512, 2) void gemm8(const bf16* __restrict__ A,
                                                const bf16* __restrict__ Bw,
                                                const float* __restrict__ b0,
                                                const float* __restrict__ b1,
                                                const float* __restrict__ b2,
                                                TO* __restrict__ out,
                                                int N, int K) {
    constexpr int RW  = BM / WM;
    constexpr int CW  = BN / WN;
    constexpr int FM  = RW / 16;
    constexpr int FN  = CW / 16;
    constexpr int FMH = FM / 2;
    constexpr int FNH0 = (FN + 1) / 2, FNH1 = FN - FNH0;
    constexpr int SZ0 = FNH0 * 16, SZ1 = FNH1 * 16;
    constexpr int AROWS_H = BM / 2;
    constexpr int B0ROWS = WN * SZ0, B1ROWS = WN * SZ1;
    constexpr int LA  = AROWS_H / 64;
    constexpr int LB0 = B0ROWS / 64, LB1 = B1ROWS / 64;
    constexpr int V0  = 2 * LA + LB0;
    constexpr int V3  = 2 * LA + LB0 + LB1;
    constexpr int V3T = LA + LB1;

    __shared__ __align__(16) bf16 AS[2 * BM * 64];
    __shared__ __align__(16) bf16 BS[2 * BN * 64];

    const int tid  = threadIdx.x;
    const int wave = tid >> 6;
    const int lane = tid & 63;
    const int quad = lane >> 4;
    const int l16  = lane & 15;
    const int wm   = wave / WN;
    const int wn   = wave % WN;

    const int gx   = gridDim.x;
    const int orig = blockIdx.y * gx + blockIdx.x;
    int row_p, col_p;
    if (gx == 32 && gridDim.y == 8) {
        // 2D XCD tiling: XCD owns 4 row-panels x 8 col-panels
        int xcd = orig & 7, idx = orig >> 3;
        row_p = ((xcd >> 2) << 2) + (idx >> 3);
        col_p = ((xcd & 3) << 3) + (idx & 7);
    } else {
        int nwg = gx * gridDim.y;
        int wg = orig;
        if ((nwg & 7) == 0) wg = (orig & 7) * (nwg >> 3) + (orig >> 3);
        row_p = wg / gx;
        col_p = wg % gx;
    }
    const int row0 = row_p * BM;
    const int col0 = col_p * BN;

    auto stageA = [&](int mh, int bufv, int kt) {
#pragma unroll
        for (int j = 0; j < LA; ++j) {
            int c = j * 512 + tid;
            int r = c >> 3, pg = c & 7;
            int g = pg ^ (r & 7);
            int gr = (r / (RW / 2)) * RW + mh * (RW / 2) + (r % (RW / 2));
            load_lds16(&A[(size_t)(row0 + gr) * K + kt * 64 + g * 8],
                       &AS[bufv * (BM * 64) + mh * (AROWS_H * 64) + c * 8]);
        }
    };
    auto stageB0 = [&](int bufv, int kt) {
#pragma unroll
        for (int j = 0; j < LB0; ++j) {
            int c = j * 512 + tid;
            int r = c >> 3, pg = c & 7;
            int g = pg ^ (r & 7);
            int gc = (r / SZ0) * CW + (r % SZ0);
            load_lds16(&Bw[(size_t)(col0 + gc) * K + kt * 64 + g * 8],
                       &BS[bufv * (BN * 64) + c * 8]);
        }
    };
    auto stageB1 = [&](int bufv, int kt) {
#pragma unroll
        for (int j = 0; j < LB1; ++j) {
            int c = j * 512 + tid;
            int r = c >> 3, pg = c & 7;
            int g = pg ^ (r & 7);
            int gc = (r / SZ1) * CW + SZ0 + (r % SZ1);
            load_lds16(&Bw[(size_t)(col0 + gc) * K + kt * 64 + g * 8],
                       &BS[bufv * (BN * 64) + B0ROWS * 64 + c * 8]);
        }
    };

    f32x4 acc[FM][FN];
#pragma unroll
    for (int mi = 0; mi < FM; ++mi)
#pragma unroll
        for (int ni = 0; ni < FN; ++ni) { f32x4 z = {0.f, 0.f, 0.f, 0.f}; acc[mi][ni] = z; }

    bf16x8 af[FMH][2];
    bf16x8 bfv[FN][2];

    auto loadA = [&](int mh, int bufv) {
#pragma unroll
        for (int mi = 0; mi < FMH; ++mi)
#pragma unroll
            for (int ks = 0; ks < 2; ++ks) {
                int r = wm * (RW / 2) + mi * 16 + l16;
                int g = ks * 4 + quad;
                af[mi][ks] = *(const bf16x8*)&AS[bufv * (BM * 64) + mh * (AROWS_H * 64) +
                                                 r * 64 + ((g ^ (r & 7)) << 3)];
            }
    };
    auto loadB = [&](auto cNH, int bufv) {
        constexpr int NHv = decltype(cNH)::value;
        constexpr int CNT = NHv ? FNH1 : FNH0;
        constexpr int SZ  = NHv ? SZ1 : SZ0;
#pragma unroll
        for (int nj = 0; nj < CNT; ++nj)
#pragma unroll
            for (int ks = 0; ks < 2; ++ks) {
                int r = wn * SZ + nj * 16 + l16;
                int g = ks * 4 + quad;
                bfv[NHv * FNH0 + nj][ks] =
                    *(const bf16x8*)&BS[bufv * (BN * 64) + NHv * (B0ROWS * 64) +
                                        r * 64 + ((g ^ (r & 7)) << 3)];
            }
    };
    auto mmac = [&](auto cMH, auto cNH) {
        constexpr int MH = decltype(cMH)::value, NHv = decltype(cNH)::value;
        constexpr int NB = NHv ? FNH0 : 0, NE = NHv ? FN : FNH0;
        __builtin_amdgcn_s_setprio(1);
#pragma unroll
        for (int mi = 0; mi < FMH; ++mi)
#pragma unroll
            for (int ni = NB; ni < NE; ++ni)
#pragma unroll
                for (int ks = 0; ks < 2; ++ks)
                    acc[MH * FMH + mi][ni] = __builtin_amdgcn_mfma_f32_16x16x32_bf16(
                        af[mi][ks], bfv[ni][ks], acc[MH * FMH + mi][ni], 0, 0, 0);
        __builtin_amdgcn_s_setprio(0);
    };

    auto run_tile = [&](int t, auto cSA1, auto cSB1, auto cSA0, auto cSB0,
                        auto cV0, auto cV3) {
        const int buf = t & 1, nbuf = buf ^ 1;
        loadA(0, buf);
        loadB(IC<0>{}, buf);
        if constexpr (decltype(cSA1)::value) stageA(1, nbuf, t + 1);
        __builtin_amdgcn_s_barrier();
        lgkm0();
        mmac(IC<0>{}, IC<0>{});
        vmwait_if<decltype(cV0)::value>();
        __builtin_amdgcn_s_barrier();
        loadB(IC<1>{}, buf);
        if constexpr (decltype(cSB1)::value) stageB1(nbuf, t + 1);
        __builtin_amdgcn_s_barrier();
        lgkm0();
        mmac(IC<0>{}, IC<1>{});
        __builtin_amdgcn_s_barrier();
        loadA(1, buf);
        if constexpr (decltype(cSA0)::value) stageA(0, buf, t + 2);
        __builtin_amdgcn_s_barrier();
        lgkm0();
        mmac(IC<1>{}, IC<0>{});
        __builtin_amdgcn_s_barrier();
        if constexpr (decltype(cSB0)::value) stageB0(buf, t + 2);
        __builtin_amdgcn_s_barrier();
        lgkm0();
        mmac(IC<1>{}, IC<1>{});
        vmwait_if<decltype(cV3)::value>();
        __builtin_amdgcn_s_barrier();
    };

    stageA(0, 0, 0); stageB0(0, 0);
    stageA(1, 0, 0); stageB1(0, 0);
    stageA(0, 1, 1); stageB0(1, 1);
    vmwait_if<V3>();
    __builtin_amdgcn_s_barrier();

    const int NT = K >> 6;
    for (int t = 0; t < NT - 2; ++t)
        run_tile(t, IC<1>{}, IC<1>{}, IC<1>{}, IC<1>{}, IC<V0>{}, IC<V3>{});
    run_tile(NT - 2, IC<1>{}, IC<1>{}, IC<0>{}, IC<0>{}, IC<V0>{}, IC<V3T>{});
    run_tile(NT - 1, IC<0>{}, IC<0>{}, IC<0>{}, IC<0>{}, IC<0>{}, IC<-1>{});

#pragma unroll
    for (int ni = 0; ni < FN; ++ni) {
        int n = col0 + wn * CW + ni * 16 + l16;
        float bv;
        if (BMODE == 0) bv = b0[n];
        else bv = (n < 4096) ? b0[n] : ((n < 5120) ? b1[n - 4096] : b2[n - 5120]);
#pragma unroll
        for (int mi = 0; mi < FM; ++mi) {
            int m = row0 + wm * RW + mi * 16 + quad * 4;
#pragma unroll
            for (int reg = 0; reg < 4; ++reg)
                out[(size_t)(m + reg) * N + n] = (TO)(acc[mi][ni][reg] + bv);
        }
    }
}

// ---------------------------------------------------------------------------
// prep: fused {LayerNorm(HD=128)+RoPE in place} + {v -> vT transpose}.
// Blocks [0,5120): LN+RoPE, 16 rows each (4 waves x 4 row-iterations).
// Blocks [5120,5632): 64x64 transpose tiles (16 col-tiles x 32 s-tiles).
// Branch is block-uniform; disjoint data.
// ---------------------------------------------------------------------------
__global__ __launch_bounds__(256) void prep(bf16* __restrict__ qkv,
                                            bf16* __restrict__ vT,
                                            const float* __restrict__ qg, const float* __restrict__ qbt,
                                            const float* __restrict__ kg, const float* __restrict__ kbt) {
    __shared__ bf16 Ts[64 * 64];
    const int b   = blockIdx.x;
    const int tid = threadIdx.x;

    if (b < 5120) {
        int lane = tid & 63;
#pragma unroll
        for (int rr = 0; rr < 4; ++rr) {
            int row = b * 16 + rr * 4 + (tid >> 6);
            bf16* ptr;
            const float *g, *bb;
            int s;
            float osc;
            if (row < S_LEN * NH) {
                s   = row >> 5;
                ptr = qkv + (size_t)s * QSTR + (row & 31) * HD;
                g   = qg; bb = qbt; osc = QSCL;
            } else {
                int r2 = row - S_LEN * NH;
                s   = r2 >> 3;
                ptr = qkv + (size_t)s * QSTR + 4096 + (r2 & 7) * HD;
                g   = kg; bb = kbt; osc = 1.f;
            }

            float x1 = (float)ptr[lane];
            float x2 = (float)ptr[lane + 64];
            float sum = x1 + x2;
            float sq  = x1 * x1 + x2 * x2;
#pragma unroll
            for (int m = 1; m < 64; m <<= 1) {
                sum += __shfl_xor(sum, m);
                sq  += __shfl_xor(sq, m);
            }
            float mu  = sum * (1.f / 128.f);
            float var = sq * (1.f / 128.f) - mu * mu;
            float rs  = rsqrtf(var + 1e-5f);
            float n1  = (x1 - mu) * rs * g[lane] + bb[lane];
            float n2  = (x2 - mu) * rs * g[lane + 64] + bb[lane + 64];

            // 500000^(-lane/64) = exp2(-lane * log2(5e5)/64)
            float inv = exp2f(-0.2958057514f * (float)lane);
            float ang = (float)s * inv;
            float sn, cs;
            sincosf(ang, &sn, &cs);

            ptr[lane]      = (bf16)((n1 * cs - n2 * sn) * osc);
            ptr[lane + 64] = (bf16)((n2 * cs + n1 * sn) * osc);
        }
    } else {
        const int t  = b - 5120;
        const int c0 = (t & 15) * 64;
        const int s0 = (t >> 4) * 64;

#pragma unroll
        for (int i = 0; i < 2; ++i) {
            int cc = i * 256 + tid;
            int r = cc >> 3, col8 = cc & 7;
            *(bf16x8*)&Ts[r * 64 + ((col8 ^ (r & 7)) << 3)] =
                *(const bf16x8*)&qkv[(size_t)(s0 + r) * QSTR + 5120 + c0 + (col8 << 3)];
        }
        __syncthreads();
#pragma unroll
        for (int i = 0; i < 2; ++i) {
            int oc = i * 256 + tid;
            int c = oc & 63, sb = oc >> 6;
            bf16x8 r8;
#pragma unroll
            for (int j = 0; j < 8; ++j) {
                int sg = sb * 8 + j;
                r8[j] = Ts[sg * 64 + ((((c >> 3) ^ (sg & 7)) << 3) + (c & 7))];
            }
            *(bf16x8*)&vT[(size_t)(c0 + c) * S_LEN + s0 + sb * 8] = r8;
        }
    }
}

// ---------------------------------------------------------------------------
// Flash attention v6 (proven round 9): split-parity, async gload_lds staging
// with counted vmcnt, in-LDS merge. LDS = 128 KiB.
// ---------------------------------------------------------------------------
__global__ __launch_bounds__(512) void attn6(const bf16* __restrict__ qkv,
                                             const bf16* __restrict__ vT,
                                             bf16* __restrict__ abuf) {
    const int pairp = blockIdx.x;
    const int kvh   = blockIdx.y;
    const int tid   = threadIdx.x;
    const int wave  = tid >> 6;
    const int lane  = tid & 63;
    const int quad  = lane >> 4;
    const int l16   = lane & 15;
    const int spw   = wave >> 2;       // kt parity this wave handles
    const int hw    = wave & 3;        // head within kv group
    const int h     = kvh * 4 + hw;

    // LDS: K[2buf][2tp][64*128] | V[2tp][128*64] | Ps[8][32*64] = 128 KiB
    __shared__ __align__(16) bf16 smem[4 * 8192 + 2 * 8192 + 8 * 2048];
    bf16* Ksb = smem;                  // slot (kbuf*2+tp)*8192
    bf16* Vtb = smem + 4 * 8192;       // slot tp*8192
    bf16* Psb = smem + 6 * 8192;       // per-wave stride 2048

    bf16x8 onesf;
#pragma unroll
    for (int j = 0; j < 8; ++j) onesf[j] = (bf16)1.f;

    auto stageK = [&](int pr, int kb) {
#pragma unroll
        for (int j = 0; j < 4; ++j) {
            int c = j * 512 + tid;
            int tile = c >> 10, cc = c & 1023;
            int key = cc >> 4, pg = cc & 15;
            int g = pg ^ (key & 7);
            load_lds16(&qkv[(size_t)((2 * pr + tile) * 64 + key) * QSTR + 4096 +
                            kvh * HD + g * 8],
                       &Ksb[(kb * 2 + tile) * 8192 + cc * 8]);
        }
    };
    auto stageV = [&](int pr) {
#pragma unroll
        for (int j = 0; j < 4; ++j) {
            int c = j * 512 + tid;
            int tile = c >> 10, cc = c & 1023;
            int d = cc >> 3, pg = cc & 7;
            int g = pg ^ (d & 7);
            load_lds16(&vT[(size_t)(kvh * HD + d) * S_LEN + (2 * pr + tile) * 64 + g * 8],
                       &Vtb[tile * 8192 + cc * 8]);
        }
    };

    for (int ph = 0; ph < 2; ++ph) {
        const int qt  = ph ? (63 - pairp) : pairp;
        const int r0  = qt * 32;
        const int nkt = qt / 2 + 1;
        const int nit = (nkt + 1) >> 1;    // K/V tile PAIRS

        // Q fragments (already scaled by QSCL in prep)
        bf16x8 qf[2][4];
#pragma unroll
        for (int mi = 0; mi < 2; ++mi)
#pragma unroll
            for (int ks = 0; ks < 4; ++ks)
                qf[mi][ks] = *(const bf16x8*)&qkv[(size_t)(r0 + mi * 16 + l16) * QSTR +
                                                  h * HD + ks * 32 + quad * 8];

        f32x4 o_acc[2][8];
#pragma unroll
        for (int mi = 0; mi < 2; ++mi)
#pragma unroll
            for (int ni = 0; ni < 8; ++ni) {
                f32x4 z = {0.f, 0.f, 0.f, 0.f};
                o_acc[mi][ni] = z;
            }
        f32x4 lacc[2];
#pragma unroll
        for (int mi = 0; mi < 2; ++mi) { f32x4 z = {0.f, 0.f, 0.f, 0.f}; lacc[mi] = z; }

        stageK(0, 0);                     // prologue: K pair 0 -> kbuf 0

        for (int it = 0; it < nit; ++it) {
            const int kb = it & 1;
            stageV(it);
            if (it + 1 < nit) { stageK(it + 1, kb ^ 1); vmwait_if<8>(); }
            else              { vmwait_if<4>(); }
            __syncthreads();              // K(it) visible to all

            const int kt = 2 * it + spw;
            const bf16* Kw = Ksb + (kb * 2 + spw) * 8192;
            const bf16* Vw = Vtb + spw * 8192;
            bf16* Pw = Psb + wave * 2048;

            if (kt < nkt) {
                f32x4 sacc[2][4];
#pragma unroll
                for (int mi = 0; mi < 2; ++mi)
#pragma unroll
                    for (int ni = 0; ni < 4; ++ni) {
                        f32x4 z = {0.f, 0.f, 0.f, 0.f};
                        sacc[mi][ni] = z;
                    }
                __builtin_amdgcn_s_setprio(1);
#pragma unroll
                for (int ks = 0; ks < 4; ++ks)
#pragma unroll
                    for (int ni = 0; ni < 4; ++ni) {
                        bf16x8 kf = *(const bf16x8*)&Kw[(ni * 16 + l16) * 128 +
                                                        ((((ks << 2) + quad) ^ (l16 & 7)) << 3)];
                        sacc[0][ni] = __builtin_amdgcn_mfma_f32_16x16x32_bf16(qf[0][ks], kf, sacc[0][ni], 0, 0, 0);
                        sacc[1][ni] = __builtin_amdgcn_mfma_f32_16x16x32_bf16(qf[1][ks], kf, sacc[1][ni], 0, 0, 0);
                    }
                __builtin_amdgcn_s_setprio(0);

#pragma unroll
                for (int mi = 0; mi < 2; ++mi)
#pragma unroll
                    for (int reg = 0; reg < 4; ++reg) {
                        int rloc = mi * 16 + quad * 4 + reg;
                        int qrow = r0 + rloc;
#pragma unroll
                        for (int ni = 0; ni < 4; ++ni) {
                            int key = kt * 64 + ni * 16 + l16;
                            float t = (key > qrow) ? -1e30f : (sacc[mi][ni][reg] - M2C);
                            float p = exp2f(t);
                            int blk = (ni * 2 + (l16 >> 3)) ^ (rloc & 7);
                            Pw[rloc * 64 + blk * 8 + (l16 & 7)] = (bf16)p;
                        }
                    }
            }

            if (it + 1 < nit) vmwait_if<4>();   // V(it) retired (K(it+1) newer)
            else              vmwait_if<0>();
            __syncthreads();              // V(it) visible to all

            if (kt < nkt) {
                __builtin_amdgcn_s_setprio(1);
#pragma unroll
                for (int ks2 = 0; ks2 < 2; ++ks2) {
                    bf16x8 pa[2];
#pragma unroll
                    for (int mi = 0; mi < 2; ++mi) {
                        int rloc = mi * 16 + l16;
                        pa[mi] = *(const bf16x8*)&Pw[rloc * 64 +
                                                     ((((ks2 << 2) + quad) ^ (rloc & 7)) << 3)];
                    }
#pragma unroll
                    for (int ni = 0; ni < 8; ++ni) {
                        int d = ni * 16 + l16;
                        bf16x8 vf = *(const bf16x8*)&Vw[d * 64 + ((((ks2 << 2) + quad) ^ (d & 7)) << 3)];
                        o_acc[0][ni] = __builtin_amdgcn_mfma_f32_16x16x32_bf16(pa[0], vf, o_acc[0][ni], 0, 0, 0);
                        o_acc[1][ni] = __builtin_amdgcn_mfma_f32_16x16x32_bf16(pa[1], vf, o_acc[1][ni], 0, 0, 0);
                    }
                    lacc[0] = __builtin_amdgcn_mfma_f32_16x16x32_bf16(pa[0], onesf, lacc[0], 0, 0, 0);
                    lacc[1] = __builtin_amdgcn_mfma_f32_16x16x32_bf16(pa[1], onesf, lacc[1], 0, 0, 0);
                }
                __builtin_amdgcn_s_setprio(0);
            }
            __syncthreads();              // PV done before next stageV/stageK
        }

        // cross-parity merge via LDS (K region = 64 KiB fp32 scratch; Ls in V region)
        float* M  = (float*)smem;
        float* Ls = (float*)&smem[4 * 8192];
        if (spw == 1) {
            float* Mw = M + hw * 4096;
#pragma unroll
            for (int mi = 0; mi < 2; ++mi)
#pragma unroll
                for (int ni = 0; ni < 8; ++ni)
#pragma unroll
                    for (int j = 0; j < 4; ++j)
                        Mw[((mi * 8 + ni) * 4 + j) * 64 + lane] = o_acc[mi][ni][j];
            if (l16 == 0)
#pragma unroll
                for (int mi = 0; mi < 2; ++mi)
#pragma unroll
                    for (int reg = 0; reg < 4; ++reg)
                        Ls[hw * 32 + mi * 16 + quad * 4 + reg] = lacc[mi][reg];
        }
        __syncthreads();
        if (spw == 0) {
            float* Mw = M + hw * 4096;
#pragma unroll
            for (int mi = 0; mi < 2; ++mi) {
                float linv[4];
#pragma unroll
                for (int reg = 0; reg < 4; ++reg)
                    linv[reg] = 1.f / fmaxf(lacc[mi][reg] +
                                            Ls[hw * 32 + mi * 16 + quad * 4 + reg], 1e-30f);
#pragma unroll
                for (int ni = 0; ni < 8; ++ni)
#pragma unroll
                    for (int reg = 0; reg < 4; ++reg) {
                        float v = o_acc[mi][ni][reg] + Mw[((mi * 8 + ni) * 4 + reg) * 64 + lane];
                        int s = r0 + mi * 16 + quad * 4 + reg;
                        abuf[(size_t)s * HID + h * HD + ni * 16 + l16] = (bf16)(v * linv[reg]);
                    }
            }
        }
        __syncthreads();
    }
}

// ===========================================================================
// Fallback path — only if workspace is unexpectedly small.
// ===========================================================================
template <typename TA, typename TO>
__global__ __launch_bounds__(256) void gemm_bt(const TA* __restrict__ A,
                                               const float* __restrict__ W,
                                               const float* __restrict__ bias,
                                               TO* __restrict__ out,
                                               int N, int K) {
    __shared__ __align__(16) bf16 As[128 * 64];
    __shared__ __align__(16) bf16 Bs[128 * 64];
    const int tid = threadIdx.x, wave = tid >> 6, lane = tid & 63;
    const int quad = lane >> 4, l16 = lane & 15, wm = wave >> 1, wn = wave & 1;
    const int row0 = blockIdx.y * 128, col0 = blockIdx.x * 128;
    f32x4 acc[4][4];
#pragma unroll
    for (int mi = 0; mi < 4; ++mi)
#pragma unroll
        for (int ni = 0; ni < 4; ++ni) { f32x4 z = {0.f,0.f,0.f,0.f}; acc[mi][ni] = z; }
    for (int k0 = 0; k0 < K; k0 += 64) {
#pragma unroll
        for (int i = 0; i < 4; ++i) {
            int c = i * 256 + tid, r = c >> 3, col8 = (c & 7) << 3;
            *(bf16x8*)&As[r * 64 + col8] = load8(&A[(size_t)(row0 + r) * K + k0 + col8]);
            *(bf16x8*)&Bs[r * 64 + col8] = load8(&W[(size_t)(col0 + r) * K + k0 + col8]);
        }
        __syncthreads();
#pragma unroll
        for (int ks = 0; ks < 2; ++ks) {
            bf16x8 af[4], bfr[4];
#pragma unroll
            for (int mi = 0; mi < 4; ++mi)
                af[mi] = *(const bf16x8*)&As[(wm * 64 + mi * 16 + l16) * 64 + ks * 32 + quad * 8];
#pragma unroll
            for (int ni = 0; ni < 4; ++ni)
                bfr[ni] = *(const bf16x8*)&Bs[(wn * 64 + ni * 16 + l16) * 64 + ks * 32 + quad * 8];
#pragma unroll
            for (int mi = 0; mi < 4; ++mi)
#pragma unroll
                for (int ni = 0; ni < 4; ++ni)
                    acc[mi][ni] = __builtin_amdgcn_mfma_f32_16x16x32_bf16(af[mi], bfr[ni], acc[mi][ni], 0, 0, 0);
        }
        __syncthreads();
    }
#pragma unroll
    for (int ni = 0; ni < 4; ++ni) {
        int n = col0 + wn * 64 + ni * 16 + l16;
        float bv = bias[n];
#pragma unroll
        for (int mi = 0; mi < 4; ++mi) {
            int m = row0 + wm * 64 + mi * 16 + quad * 4;
#pragma unroll
            for (int reg = 0; reg < 4; ++reg)
                out[(size_t)(m + reg) * N + n] = (TO)(acc[mi][ni][reg] + bv);
        }
    }
}

__global__ __launch_bounds__(256) void ln_rope_f(bf16* __restrict__ qb, bf16* __restrict__ kb,
                                                 const float* __restrict__ qg, const float* __restrict__ qbt,
                                                 const float* __restrict__ kg, const float* __restrict__ kbt) {
    int row = blockIdx.x * 4 + (threadIdx.x >> 6);
    int lane = threadIdx.x & 63;
    bf16* ptr; const float *g, *bb; int s;
    if (row < S_LEN * NH) { s = row >> 5; ptr = qb + (size_t)s * (NH * HD) + (row & 31) * HD; g = qg; bb = qbt; }
    else { int r2 = row - S_LEN * NH; s = r2 >> 3; ptr = kb + (size_t)s * (NKV * HD) + (r2 & 7) * HD; g = kg; bb = kbt; }
    float x1 = (float)ptr[lane], x2 = (float)ptr[lane + 64];
    float sum = x1 + x2, sq = x1 * x1 + x2 * x2;
#pragma unroll
    for (int m = 1; m < 64; m <<= 1) { sum += __shfl_xor(sum, m); sq += __shfl_xor(sq, m); }
    float mu = sum * (1.f / 128.f), var = sq * (1.f / 128.f) - mu * mu;
    float rs = rsqrtf(var + 1e-5f);
    float n1 = (x1 - mu) * rs * g[lane] + bb[lane];
    float n2 = (x2 - mu) * rs * g[lane + 64] + bb[lane + 64];
    float inv = powf(500000.f, -(float)lane * (1.f / 64.f));
    float ang = (float)s * inv, sn, cs;
    sincosf(ang, &sn, &cs);
    ptr[lane] = (bf16)(n1 * cs - n2 * sn);
    ptr[lane + 64] = (bf16)(n2 * cs + n1 * sn);
}

__global__ __launch_bounds__(256) void attn_old(const bf16* __restrict__ qbuf,
                                                const bf16* __restrict__ kbuf,
                                                const bf16* __restrict__ vbuf,
                                                bf16* __restrict__ obuf) {
    const int qi = blockIdx.x, hh = blockIdx.y, kvh = hh >> 2;
    __shared__ __align__(16) bf16 Qs[64 * 128];
    __shared__ __align__(16) bf16 Ks2[64 * 128];
    __shared__ __align__(16) bf16 Vt2[128 * 80];
    __shared__ __align__(16) float Ss[64 * 64];
    __shared__ __align__(16) bf16 Ps2[64 * 64];
    __shared__ float mS[64], lS[64], aS[64];
    const int tid = threadIdx.x, wave = tid >> 6, lane = tid & 63;
    const int quad = lane >> 4, l16 = lane & 15;
#pragma unroll
    for (int i = 0; i < 4; ++i) {
        int c = i * 256 + tid, r = c >> 4, col8 = (c & 15) << 3;
        *(int4*)&Qs[r * 128 + col8] = *(const int4*)&qbuf[(size_t)(qi * 64 + r) * HID + hh * HD + col8];
    }
    if (tid < 64) { mS[tid] = -1e30f; lS[tid] = 0.f; }
    f32x4 o_acc[8];
#pragma unroll
    for (int i = 0; i < 8; ++i) { f32x4 z = {0.f,0.f,0.f,0.f}; o_acc[i] = z; }
    __syncthreads();
    for (int kt = 0; kt <= qi; ++kt) {
#pragma unroll
        for (int i = 0; i < 4; ++i) {
            int c = i * 256 + tid, r = c >> 4, col8 = (c & 15) << 3;
            const size_t gofs = (size_t)(kt * 64 + r) * (NKV * HD) + kvh * HD + col8;
            *(int4*)&Ks2[r * 128 + col8] = *(const int4*)&kbuf[gofs];
            bf16x8 vv = *(const bf16x8*)&vbuf[gofs];
#pragma unroll
            for (int e = 0; e < 8; ++e) Vt2[(col8 + e) * 80 + r] = vv[e];
        }
        __syncthreads();
        f32x4 sacc[4];
#pragma unroll
        for (int ni = 0; ni < 4; ++ni) { f32x4 z = {0.f,0.f,0.f,0.f}; sacc[ni] = z; }
#pragma unroll
        for (int ks = 0; ks < 4; ++ks) {
            bf16x8 a = *(const bf16x8*)&Qs[(wave * 16 + l16) * 128 + ks * 32 + quad * 8];
#pragma unroll
            for (int ni = 0; ni < 4; ++ni) {
                bf16x8 b = *(const bf16x8*)&Ks2[(ni * 16 + l16) * 128 + ks * 32 + quad * 8];
                sacc[ni] = __builtin_amdgcn_mfma_f32_16x16x32_bf16(a, b, sacc[ni], 0, 0, 0);
            }
        }
#pragma unroll
        for (int ni = 0; ni < 4; ++ni)
#pragma unroll
            for (int reg = 0; reg < 4; ++reg) {
                int r = wave * 16 + quad * 4 + reg, cc = ni * 16 + l16;
                float sv = sacc[ni][reg] * SCALE;
                if (kt * 64 + cc > qi * 64 + r) sv = -1e30f;
                Ss[r * 64 + cc] = sv;
            }
        __syncthreads();
        {
            int r = tid >> 2, j = tid & 3;
            float vals[16], mloc = -1e30f;
#pragma unroll
            for (int c = 0; c < 16; ++c) { vals[c] = Ss[r * 64 + j * 16 + c]; mloc = fmaxf(mloc, vals[c]); }
            mloc = fmaxf(mloc, __shfl_xor(mloc, 1));
            mloc = fmaxf(mloc, __shfl_xor(mloc, 2));
            float mold = mS[r], mnew = fmaxf(mold, mloc), ssum = 0.f;
#pragma unroll
            for (int c = 0; c < 16; ++c) {
                float p = __expf(vals[c] - mnew);
                ssum += p;
                Ps2[r * 64 + j * 16 + c] = (bf16)p;
            }
            ssum += __shfl_xor(ssum, 1);
            ssum += __shfl_xor(ssum, 2);
            if (j == 0) { float alpha = __expf(mold - mnew); mS[r] = mnew; lS[r] = lS[r] * alpha + ssum; aS[r] = alpha; }
        }
        __syncthreads();
        {
            float al2[4];
#pragma unroll
            for (int reg = 0; reg < 4; ++reg) al2[reg] = aS[wave * 16 + quad * 4 + reg];
#pragma unroll
            for (int ni = 0; ni < 8; ++ni)
#pragma unroll
                for (int reg = 0; reg < 4; ++reg) o_acc[ni][reg] *= al2[reg];
#pragma unroll
            for (int ks = 0; ks < 2; ++ks) {
                bf16x8 a = *(const bf16x8*)&Ps2[(wave * 16 + l16) * 64 + ks * 32 + quad * 8];
#pragma unroll
                for (int ni = 0; ni < 8; ++ni) {
                    bf16x8 b = *(const bf16x8*)&Vt2[(ni * 16 + l16) * 80 + ks * 32 + quad * 8];
                    o_acc[ni] = __builtin_amdgcn_mfma_f32_16x16x32_bf16(a, b, o_acc[ni], 0, 0, 0);
                }
            }
        }
        __syncthreads();
    }
    {
        float linv[4];
#pragma unroll
        for (int reg = 0; reg < 4; ++reg) linv[reg] = 1.f / fmaxf(lS[wave * 16 + quad * 4 + reg], 1e-20f);
#pragma unroll
        for (int ni = 0; ni < 8; ++ni)
#pragma unroll
            for (int reg = 0; reg < 4; ++reg) {
                int r = wave * 16 + quad * 4 + reg;
                obuf[(size_t)(qi * 64 + r) * HID + hh * HD + ni * 16 + l16] = (bf16)(o_acc[ni][reg] * linv[reg]);
            }
    }
}

// ---------------------------------------------------------------------------
extern "C" void kernel_launch(void* const* d_in, const int* in_sizes, int n_in,
                              void* d_out, int out_size, void* d_ws, size_t ws_size,
                              hipStream_t stream) {
    const float* x   = (const float*)d_in[0];
    const float* Wq  = (const float*)d_in[1];
    const float* bq  = (const float*)d_in[2];
    const float* Wk  = (const float*)d_in[3];
    const float* bk  = (const float*)d_in[4];
    const float* Wv  = (const float*)d_in[5];
    const float* bv  = (const float*)d_in[6];
    const float* Wo  = (const float*)d_in[7];
    const float* bo  = (const float*)d_in[8];
    const float* qg  = (const float*)d_in[9];
    const float* qbt = (const float*)d_in[10];
    const float* kg  = (const float*)d_in[11];
    const float* kbt = (const float*)d_in[12];
    float* out = (float*)d_out;

    // fast-path workspace layout (130,547,712 B):
    //   [0, 16MiB)           : xb  -- later aliased by abuf (attn6 bf16 out)
    //   [16MiB, 64MiB)       : Wqkv
    //   [64MiB, 96MiB)       : Wob
    //   [96MiB, 120MiB)      : qkv
    //   [120MiB, 124MiB)     : vT
    const size_t NEED = 130547712;
    if (ws_size >= NEED) {
        char* p = (char*)d_ws;
        bf16*  xb   = (bf16*)p;
        bf16*  Wqkv = (bf16*)(p + 16777216);
        bf16*  abuf = (bf16*)p;                        // aliases xb (dead after QKV gemm)
        bf16*  Wob  = (bf16*)(p + 67108864);
        bf16*  qkv  = (bf16*)(p + 100663296);
        bf16*  vT   = (bf16*)(p + 125829120);

        // fused fp32 -> bf16 of all inputs (one launch)
        cvt5<<<24576, 256, 0, stream>>>(x, Wq, Wk, Wv, Wo, xb, Wqkv, Wob);

        // fused QKV projection: [2048 x 6144], 256x192 tiles, 2D-XCD-tiled
        gemm8<256, 192, 2, 4, 1, bf16><<<dim3(32, 8), 512, 0, stream>>>(
            xb, Wqkv, bq, bk, bv, qkv, QSTR, 4096);

        // fused LN+RoPE (in place) + v -> vT transpose
        prep<<<5632, 256, 0, stream>>>(qkv, vT, qg, qbt, kg, kbt);

        // split-parity attention with async gload_lds staging + counted vmcnt
        attn6<<<dim3(32, 8), 512, 0, stream>>>(qkv, vT, abuf);

        // output projection: 256x128 tiles, 2D-XCD-tiled
        gemm8<256, 128, 4, 2, 0, float><<<dim3(32, 8), 512, 0, stream>>>(
            abuf, Wob, bo, bo, bo, out, 4096, 4096);
    } else {
        char* ws = (char*)d_ws;
        bf16* qbuf = (bf16*)(ws);
        bf16* kbuf = (bf16*)(ws + (16u << 20));
        bf16* vbuf = (bf16*)(ws + (20u << 20));
        bf16* abuf = (bf16*)(ws + (24u << 20));
        gemm_bt<float, bf16><<<dim3(32, 16), 256, 0, stream>>>(x, Wq, bq, qbuf, 4096, 4096);
        gemm_bt<float, bf16><<<dim3(8, 16), 256, 0, stream>>>(x, Wk, bk, kbuf, 1024, 4096);
        gemm_bt<float, bf16><<<dim3(8, 16), 256, 0, stream>>>(x, Wv, bv, vbuf, 1024, 4096);
        ln_rope_f<<<dim3((S_LEN * (NH + NKV)) / 4), 256, 0, stream>>>(qbuf, kbuf, qg, qbt, kg, kbt);
        attn_old<<<dim3(32, 32), 256, 0, stream>>>(qbuf, kbuf, vbuf, abuf);
        gemm_bt<bf16, float><<<dim3(32, 16), 256, 0, stream>>>(abuf, Wo, bo, out, 4096, 4096);
    }
}